// Round 3
// baseline (1524.810 us; speedup 1.0000x reference)
//
#include <hip/hip_runtime.h>
#include <hip/hip_bf16.h>

#define C 128            // C_IN == C_OUT == 128
#define TPB 256
#define BM 128           // gemm rows per block
#define BK 32            // gemm k-tile

// ---------------- workspace layout (bytes) ----------------
#define OFF_FLAG 0x0
#define OFF_DEGD 0x400       // int[N]   in-degree (by dst)
#define OFF_CNTS 0x80000     // int[N]   out-degree (by src)
#define OFF_INVD 0x100000    // float[N] 1/(degD+1)
#define OFF_OFFS 0x180000    // int[N]   CSR row offsets (exclusive scan of cntS)
#define OFF_CUR  0x200000    // int[N]   fill cursors (init = offS)
#define OFF_BSUM 0x280000    // int[512] scan partials
#define OFF_EDST 0x300000    // int[E]   CSR adjacency (dst per slot)
#define OFF_HN   0xA00000    // bf16[N*128] hn = (x@W^T) * invd

__device__ __forceinline__ unsigned f2bf_bits(float f) {
    unsigned u = __float_as_uint(f);
    return (u + 0x7fffu + ((u >> 16) & 1u)) >> 16;   // RNE
}
__device__ __forceinline__ float2 bf2f(unsigned u) {
    return make_float2(__uint_as_float(u << 16), __uint_as_float(u & 0xffff0000u));
}

// Detect whether edge_index is int64 (high 32-bit words all zero) or int32.
__global__ void detect_kernel(const unsigned int* __restrict__ ew, int nCheck,
                              int* __restrict__ flagp) {
    __shared__ int s;
    if (threadIdx.x == 0) s = 0;
    __syncthreads();
    int any = 0;
    for (int i = threadIdx.x; i < nCheck; i += TPB)
        any |= (ew[2 * i + 1] != 0u);
    if (any) s = 1;              // some high word nonzero -> int32 layout
    __syncthreads();
    if (threadIdx.x == 0) *flagp = s;
}

__device__ __forceinline__ void load_edge(const void* edges, long long E, int is32,
                                          long long e, int& s, int& d) {
    if (is32) {
        const int* p = (const int*)edges;
        s = p[e]; d = p[E + e];
    } else {
        const long long* p = (const long long*)edges;
        s = (int)p[e]; d = (int)p[E + e];
    }
}

__global__ void zero2_kernel(int* degD, int* cntS, int N) {
    int i = blockIdx.x * TPB + threadIdx.x;
    if (i < N) { degD[i] = 0; cntS[i] = 0; }
}

__global__ void count_kernel(const void* __restrict__ edges, const int* __restrict__ flagp,
                             long long E, int* __restrict__ degD, int* __restrict__ cntS) {
    long long e = (long long)blockIdx.x * TPB + threadIdx.x;
    if (e >= E) return;
    int s, d;
    load_edge(edges, E, *flagp, e, s, d);
    atomicAdd(&degD[d], 1);
    atomicAdd(&cntS[s], 1);
}

__global__ void invd_kernel(const int* __restrict__ degD, float* __restrict__ invd, int N) {
    int i = blockIdx.x * TPB + threadIdx.x;
    if (i < N) invd[i] = 1.0f / (float)(degD[i] + 1);
}

// exclusive scan of cntS -> offS ; per-block totals -> bsum
__global__ __launch_bounds__(TPB) void scan1_kernel(const int* __restrict__ cntS,
                                                    int* __restrict__ offS,
                                                    int* __restrict__ bsum, int N) {
    __shared__ int s[TPB];
    const int t = threadIdx.x;
    const int i = blockIdx.x * TPB + t;
    int v = (i < N) ? cntS[i] : 0;
    s[t] = v;
    __syncthreads();
    for (int d = 1; d < TPB; d <<= 1) {
        int add = (t >= d) ? s[t - d] : 0;
        __syncthreads();
        s[t] += add;
        __syncthreads();
    }
    if (i < N) offS[i] = s[t] - v;                 // local exclusive
    if (t == TPB - 1) bsum[blockIdx.x] = s[t];     // block total
}

__global__ void scan2_kernel(int* __restrict__ bsum, int nb) {
    __shared__ int s[512];
    const int t = threadIdx.x;   // 512 threads
    int v = (t < nb) ? bsum[t] : 0;
    s[t] = v;
    __syncthreads();
    for (int d = 1; d < 512; d <<= 1) {
        int add = (t >= d) ? s[t - d] : 0;
        __syncthreads();
        s[t] += add;
        __syncthreads();
    }
    if (t < nb) bsum[t] = s[t] - v;                // exclusive
}

__global__ void scan3_kernel(int* __restrict__ offS, const int* __restrict__ bsum,
                             int* __restrict__ cur, int N) {
    int i = blockIdx.x * TPB + threadIdx.x;
    if (i < N) {
        int v = offS[i] + bsum[blockIdx.x];
        offS[i] = v;
        cur[i] = v;                                // cursor starts at row offset
    }
}

__global__ void fill_kernel(const void* __restrict__ edges, const int* __restrict__ flagp,
                            long long E, int* __restrict__ cur, int* __restrict__ eDst) {
    long long e = (long long)blockIdx.x * TPB + threadIdx.x;
    if (e >= E) return;
    int s, d;
    load_edge(edges, E, *flagp, e, s, d);
    int pos = atomicAdd(&cur[s], 1);
    eDst[pos] = d;
}

// hn[i][:] = bf16( (x[i] @ W^T) * invd[i] )
// 128x128 block tile, BK=32 k-tiles, 8x8 register tile per thread.
// LDS 32 KB -> 4 blocks/CU (16 waves/CU). XOR swizzle keeps b128 alignment
// and breaks the stride-128B bank conflict.
__global__ __launch_bounds__(TPB, 4) void gemm_hn_kernel(const float* __restrict__ x,
                                                         const float* __restrict__ W,
                                                         const float* __restrict__ invd,
                                                         unsigned short* __restrict__ hn,
                                                         int N) {
    __shared__ float xs[BM][BK];   // 16 KB, swizzled
    __shared__ float Ws[C][BK];    // 16 KB, swizzled
    const int t = threadIdx.x;
    const int base = blockIdx.x * BM;
    const int tc = t & 15;         // col group (16 x 8 cols)
    const int tr = t >> 4;         // row group (16 x 8 rows)

    float acc[8][8];
#pragma unroll
    for (int i = 0; i < 8; ++i)
#pragma unroll
        for (int o = 0; o < 8; ++o) acc[i][o] = 0.f;

    for (int kt = 0; kt < C; kt += BK) {
        __syncthreads();           // previous tile fully consumed
        // stage x tile: 128 rows x 32 floats, swizzled col4' = c4 ^ ((r>>3)&7)
#pragma unroll
        for (int ii = 0; ii < 4; ++ii) {
            int i = t + ii * TPB;
            int r = i >> 3, c4 = i & 7;
            int gr = base + r;
            float4 v = make_float4(0.f, 0.f, 0.f, 0.f);
            if (gr < N) v = *(const float4*)(x + (size_t)gr * C + kt + c4 * 4);
            *(float4*)&xs[r][(c4 ^ ((r >> 3) & 7)) * 4] = v;
        }
#pragma unroll
        for (int ii = 0; ii < 4; ++ii) {
            int i = t + ii * TPB;
            int r = i >> 3, c4 = i & 7;
            float4 v = *(const float4*)(W + (size_t)r * C + kt + c4 * 4);
            *(float4*)&Ws[r][(c4 ^ ((r >> 3) & 7)) * 4] = v;
        }
        __syncthreads();

#pragma unroll
        for (int k4 = 0; k4 < 8; ++k4) {
            float4 xv[8];
#pragma unroll
            for (int i = 0; i < 8; ++i)
                xv[i] = *(const float4*)&xs[tr * 8 + i][(k4 ^ (tr & 7)) * 4];
#pragma unroll
            for (int o = 0; o < 8; ++o) {
                const float4 wv = *(const float4*)&Ws[tc * 8 + o][(k4 ^ (tc & 7)) * 4];
#pragma unroll
                for (int i = 0; i < 8; ++i)
                    acc[i][o] += xv[i].x * wv.x + xv[i].y * wv.y +
                                 xv[i].z * wv.z + xv[i].w * wv.w;
            }
        }
    }

    // epilogue: scale by invd, pack to bf16, 16B stores
    const int gr0 = base + tr * 8;
#pragma unroll
    for (int i = 0; i < 8; ++i) {
        const int gr = gr0 + i;
        if (gr < N) {
            const float idv = invd[gr];
            unsigned p0 = f2bf_bits(acc[i][0] * idv) | (f2bf_bits(acc[i][1] * idv) << 16);
            unsigned p1 = f2bf_bits(acc[i][2] * idv) | (f2bf_bits(acc[i][3] * idv) << 16);
            unsigned p2 = f2bf_bits(acc[i][4] * idv) | (f2bf_bits(acc[i][5] * idv) << 16);
            unsigned p3 = f2bf_bits(acc[i][6] * idv) | (f2bf_bits(acc[i][7] * idv) << 16);
            *(uint4*)(hn + (size_t)gr * C + tc * 8) = make_uint4(p0, p1, p2, p3);
        }
    }
}

// One wave per node: out[i] = (sum_{j in adj[i]} hn[j] + hn[i]) * invd[i]
// hn rows are 128 bf16 = 64 lanes x 1 dword, fully coalesced 256B per row.
__global__ __launch_bounds__(TPB) void gather_kernel(const int* __restrict__ offS,
                                                     const int* __restrict__ cntS,
                                                     const int* __restrict__ eDst,
                                                     const unsigned* __restrict__ hnb,
                                                     const float* __restrict__ invd,
                                                     float* __restrict__ out, int N) {
    const int lane = threadIdx.x & 63;
    const int w = (blockIdx.x * TPB + threadIdx.x) >> 6;
    if (w >= N) return;
    const int beg = offS[w];
    const int cnt = cntS[w];

    float2 acc = bf2f(hnb[(size_t)w * 64 + lane]);   // self loop

    for (int j0 = 0; j0 < cnt; j0 += 64) {
        const int m = min(64, cnt - j0);
        int dl = 0;
        if (lane < m) dl = eDst[beg + j0 + lane];    // one coalesced load per 64 nbrs
        int q = 0;
#pragma unroll 1
        for (; q + 8 <= m; q += 8) {
            const int d0 = __shfl(dl, q + 0);
            const int d1 = __shfl(dl, q + 1);
            const int d2 = __shfl(dl, q + 2);
            const int d3 = __shfl(dl, q + 3);
            const int d4 = __shfl(dl, q + 4);
            const int d5 = __shfl(dl, q + 5);
            const int d6 = __shfl(dl, q + 6);
            const int d7 = __shfl(dl, q + 7);
            const unsigned v0 = hnb[(size_t)d0 * 64 + lane];
            const unsigned v1 = hnb[(size_t)d1 * 64 + lane];
            const unsigned v2 = hnb[(size_t)d2 * 64 + lane];
            const unsigned v3 = hnb[(size_t)d3 * 64 + lane];
            const unsigned v4 = hnb[(size_t)d4 * 64 + lane];
            const unsigned v5 = hnb[(size_t)d5 * 64 + lane];
            const unsigned v6 = hnb[(size_t)d6 * 64 + lane];
            const unsigned v7 = hnb[(size_t)d7 * 64 + lane];
            float2 a = bf2f(v0), b = bf2f(v1), c = bf2f(v2), d = bf2f(v3);
            float2 e = bf2f(v4), f = bf2f(v5), g = bf2f(v6), h = bf2f(v7);
            acc.x += ((a.x + b.x) + (c.x + d.x)) + ((e.x + f.x) + (g.x + h.x));
            acc.y += ((a.y + b.y) + (c.y + d.y)) + ((e.y + f.y) + (g.y + h.y));
        }
        for (; q < m; ++q) {
            const int d = __shfl(dl, q);
            const float2 v = bf2f(hnb[(size_t)d * 64 + lane]);
            acc.x += v.x; acc.y += v.y;
        }
    }
    const float s = invd[w];
    *(float2*)(out + (size_t)w * C + lane * 2) = make_float2(acc.x * s, acc.y * s);
}

extern "C" void kernel_launch(void* const* d_in, const int* in_sizes, int n_in,
                              void* d_out, int out_size, void* d_ws, size_t ws_size,
                              hipStream_t stream) {
    const float* x = (const float*)d_in[0];
    const void* edges = d_in[1];
    const float* W = (const float*)d_in[2];
    float* out = (float*)d_out;

    const int N = in_sizes[0] / C;
    const long long E = (long long)in_sizes[1] / 2;

    char* ws = (char*)d_ws;
    int*      flagp = (int*)(ws + OFF_FLAG);
    int*      degD  = (int*)(ws + OFF_DEGD);
    int*      cntS  = (int*)(ws + OFF_CNTS);
    float*    invd  = (float*)(ws + OFF_INVD);
    int*      offS  = (int*)(ws + OFF_OFFS);
    int*      cur   = (int*)(ws + OFF_CUR);
    int*      bsum  = (int*)(ws + OFF_BSUM);
    int*      eDst  = (int*)(ws + OFF_EDST);
    unsigned short* hn = (unsigned short*)(ws + OFF_HN);

    const int nBlkN = (N + TPB - 1) / TPB;                  // 391
    const int nBlkE = (int)((E + TPB - 1) / TPB);           // 6250

    int nCheck = (int)(E < 4096 ? E : 4096);
    detect_kernel<<<1, TPB, 0, stream>>>((const unsigned int*)edges, nCheck, flagp);
    zero2_kernel<<<nBlkN, TPB, 0, stream>>>(degD, cntS, N);
    count_kernel<<<nBlkE, TPB, 0, stream>>>(edges, flagp, E, degD, cntS);
    invd_kernel<<<nBlkN, TPB, 0, stream>>>(degD, invd, N);
    scan1_kernel<<<nBlkN, TPB, 0, stream>>>(cntS, offS, bsum, N);
    scan2_kernel<<<1, 512, 0, stream>>>(bsum, nBlkN);
    scan3_kernel<<<nBlkN, TPB, 0, stream>>>(offS, bsum, cur, N);
    fill_kernel<<<nBlkE, TPB, 0, stream>>>(edges, flagp, E, cur, eDst);

    const int nBlkG = (N + BM - 1) / BM;                    // 782
    gemm_hn_kernel<<<nBlkG, TPB, 0, stream>>>(x, W, invd, hn, N);

    const int nBlkA = (N * 64 + TPB - 1) / TPB;             // 25000 (wave per node)
    gather_kernel<<<nBlkA, TPB, 0, stream>>>(offS, cntS, eDst, (const unsigned*)hn,
                                             invd, out, N);
}

// Round 4
// 469.867 us; speedup vs baseline: 3.2452x; 3.2452x over previous
//
#include <hip/hip_runtime.h>
#include <hip/hip_bf16.h>

#define C 128            // C_IN == C_OUT == 128
#define TPB 256
#define BM 128           // gemm rows per block
#define BK 32            // gemm k-tile

// ---------------- workspace layout (bytes) ----------------
#define OFF_FLAG 0x0
#define OFF_DEGD 0x400       // int[N]   in-degree (by dst)
#define OFF_CNTS 0x80000     // int[N]   out-degree (by src)
#define OFF_INVD 0x100000    // float[N] 1/(degD+1)
#define OFF_OFFS 0x180000    // int[N]   CSR row offsets (exclusive scan of cntS)
#define OFF_CUR  0x200000    // int[N]   fill cursors (init = offS)
#define OFF_BSUM 0x280000    // int[512] scan partials
#define OFF_EDST 0x300000    // int[E]   CSR adjacency (dst per slot)
#define OFF_HN   0xA00000    // bf16[N*128] hn = (x@W^T) * invd

__device__ __forceinline__ unsigned f2bf_bits(float f) {
    unsigned u = __float_as_uint(f);
    return (u + 0x7fffu + ((u >> 16) & 1u)) >> 16;   // RNE
}
__device__ __forceinline__ float2 bf2f(unsigned u) {
    return make_float2(__uint_as_float(u << 16), __uint_as_float(u & 0xffff0000u));
}

// Detect whether edge_index is int64 (high 32-bit words all zero) or int32.
__global__ void detect_kernel(const unsigned int* __restrict__ ew, int nCheck,
                              int* __restrict__ flagp) {
    __shared__ int s;
    if (threadIdx.x == 0) s = 0;
    __syncthreads();
    int any = 0;
    for (int i = threadIdx.x; i < nCheck; i += TPB)
        any |= (ew[2 * i + 1] != 0u);
    if (any) s = 1;              // some high word nonzero -> int32 layout
    __syncthreads();
    if (threadIdx.x == 0) *flagp = s;
}

__device__ __forceinline__ void load_edge(const void* edges, long long E, int is32,
                                          long long e, int& s, int& d) {
    if (is32) {
        const int* p = (const int*)edges;
        s = p[e]; d = p[E + e];
    } else {
        const long long* p = (const long long*)edges;
        s = (int)p[e]; d = (int)p[E + e];
    }
}

__global__ void zero2_kernel(int* degD, int* cntS, int N) {
    int i = blockIdx.x * TPB + threadIdx.x;
    if (i < N) { degD[i] = 0; cntS[i] = 0; }
}

__global__ void count_kernel(const void* __restrict__ edges, const int* __restrict__ flagp,
                             long long E, int* __restrict__ degD, int* __restrict__ cntS) {
    long long e = (long long)blockIdx.x * TPB + threadIdx.x;
    if (e >= E) return;
    int s, d;
    load_edge(edges, E, *flagp, e, s, d);
    atomicAdd(&degD[d], 1);
    atomicAdd(&cntS[s], 1);
}

__global__ void invd_kernel(const int* __restrict__ degD, float* __restrict__ invd, int N) {
    int i = blockIdx.x * TPB + threadIdx.x;
    if (i < N) invd[i] = 1.0f / (float)(degD[i] + 1);
}

// exclusive scan of cntS -> offS ; per-block totals -> bsum
__global__ __launch_bounds__(TPB) void scan1_kernel(const int* __restrict__ cntS,
                                                    int* __restrict__ offS,
                                                    int* __restrict__ bsum, int N) {
    __shared__ int s[TPB];
    const int t = threadIdx.x;
    const int i = blockIdx.x * TPB + t;
    int v = (i < N) ? cntS[i] : 0;
    s[t] = v;
    __syncthreads();
    for (int d = 1; d < TPB; d <<= 1) {
        int add = (t >= d) ? s[t - d] : 0;
        __syncthreads();
        s[t] += add;
        __syncthreads();
    }
    if (i < N) offS[i] = s[t] - v;                 // local exclusive
    if (t == TPB - 1) bsum[blockIdx.x] = s[t];     // block total
}

__global__ void scan2_kernel(int* __restrict__ bsum, int nb) {
    __shared__ int s[512];
    const int t = threadIdx.x;   // 512 threads
    int v = (t < nb) ? bsum[t] : 0;
    s[t] = v;
    __syncthreads();
    for (int d = 1; d < 512; d <<= 1) {
        int add = (t >= d) ? s[t - d] : 0;
        __syncthreads();
        s[t] += add;
        __syncthreads();
    }
    if (t < nb) bsum[t] = s[t] - v;                // exclusive
}

__global__ void scan3_kernel(int* __restrict__ offS, const int* __restrict__ bsum,
                             int* __restrict__ cur, int N) {
    int i = blockIdx.x * TPB + threadIdx.x;
    if (i < N) {
        int v = offS[i] + bsum[blockIdx.x];
        offS[i] = v;
        cur[i] = v;                                // cursor starts at row offset
    }
}

__global__ void fill_kernel(const void* __restrict__ edges, const int* __restrict__ flagp,
                            long long E, int* __restrict__ cur, int* __restrict__ eDst) {
    long long e = (long long)blockIdx.x * TPB + threadIdx.x;
    if (e >= E) return;
    int s, d;
    load_edge(edges, E, *flagp, e, s, d);
    int pos = atomicAdd(&cur[s], 1);
    eDst[pos] = d;
}

// hn[i][:] = bf16( (x[i] @ W^T) * invd[i] )
// 128x128 block tile, BK=32 k-tiles, 8x8 register tile per thread.
// LDS 32 KB. Swizzle col' = c4 ^ (r&7) ^ ((r>>3)&7):
//   writes: r&7 varies across lanes -> 32 distinct banks, conflict-free
//   xv reads: tr&7 varies across 4 row-groups -> 4 banks, 16-lane broadcast
//   wv reads: tc&7 -> 8 bank groups, 2-way (free)
// NO min-waves clamp: launch_bounds(256,4) forced VGPR=64 -> 3.5GB scratch spill.
__global__ __launch_bounds__(TPB) void gemm_hn_kernel(const float* __restrict__ x,
                                                      const float* __restrict__ W,
                                                      const float* __restrict__ invd,
                                                      unsigned short* __restrict__ hn,
                                                      int N) {
    __shared__ float xs[BM][BK];   // 16 KB, swizzled
    __shared__ float Ws[C][BK];    // 16 KB, swizzled
    const int t = threadIdx.x;
    const int base = blockIdx.x * BM;
    const int tc = t & 15;         // col group (16 x 8 cols)
    const int tr = t >> 4;         // row group (16 x 8 rows)

    float acc[8][8];
#pragma unroll
    for (int i = 0; i < 8; ++i)
#pragma unroll
        for (int o = 0; o < 8; ++o) acc[i][o] = 0.f;

    for (int kt = 0; kt < C; kt += BK) {
        __syncthreads();           // previous tile fully consumed
#pragma unroll
        for (int ii = 0; ii < 4; ++ii) {
            int i = t + ii * TPB;
            int r = i >> 3, c4 = i & 7;
            int gr = base + r;
            float4 v = make_float4(0.f, 0.f, 0.f, 0.f);
            if (gr < N) v = *(const float4*)(x + (size_t)gr * C + kt + c4 * 4);
            *(float4*)&xs[r][(c4 ^ (r & 7) ^ ((r >> 3) & 7)) * 4] = v;
        }
#pragma unroll
        for (int ii = 0; ii < 4; ++ii) {
            int i = t + ii * TPB;
            int r = i >> 3, c4 = i & 7;
            float4 v = *(const float4*)(W + (size_t)r * C + kt + c4 * 4);
            *(float4*)&Ws[r][(c4 ^ (r & 7) ^ ((r >> 3) & 7)) * 4] = v;
        }
        __syncthreads();

#pragma unroll
        for (int k4 = 0; k4 < 8; ++k4) {
            float4 xv[8];
#pragma unroll
            for (int i = 0; i < 8; ++i)
                xv[i] = *(const float4*)&xs[tr * 8 + i][(k4 ^ i ^ (tr & 7)) * 4];
#pragma unroll
            for (int o = 0; o < 8; ++o) {
                const float4 wv = *(const float4*)&Ws[tc * 8 + o][(k4 ^ o ^ (tc & 7)) * 4];
#pragma unroll
                for (int i = 0; i < 8; ++i)
                    acc[i][o] += xv[i].x * wv.x + xv[i].y * wv.y +
                                 xv[i].z * wv.z + xv[i].w * wv.w;
            }
        }
    }

    // epilogue: scale by invd, pack to bf16, 16B stores
    const int gr0 = base + tr * 8;
#pragma unroll
    for (int i = 0; i < 8; ++i) {
        const int gr = gr0 + i;
        if (gr < N) {
            const float idv = invd[gr];
            unsigned p0 = f2bf_bits(acc[i][0] * idv) | (f2bf_bits(acc[i][1] * idv) << 16);
            unsigned p1 = f2bf_bits(acc[i][2] * idv) | (f2bf_bits(acc[i][3] * idv) << 16);
            unsigned p2 = f2bf_bits(acc[i][4] * idv) | (f2bf_bits(acc[i][5] * idv) << 16);
            unsigned p3 = f2bf_bits(acc[i][6] * idv) | (f2bf_bits(acc[i][7] * idv) << 16);
            *(uint4*)(hn + (size_t)gr * C + tc * 8) = make_uint4(p0, p1, p2, p3);
        }
    }
}

// One wave per node: out[i] = (sum_{j in adj[i]} hn[j] + hn[i]) * invd[i]
// hn rows are 128 bf16 = 64 lanes x 1 dword, fully coalesced 256B per row.
__global__ __launch_bounds__(TPB) void gather_kernel(const int* __restrict__ offS,
                                                     const int* __restrict__ cntS,
                                                     const int* __restrict__ eDst,
                                                     const unsigned* __restrict__ hnb,
                                                     const float* __restrict__ invd,
                                                     float* __restrict__ out, int N) {
    const int lane = threadIdx.x & 63;
    const int w = (blockIdx.x * TPB + threadIdx.x) >> 6;
    if (w >= N) return;
    const int beg = offS[w];
    const int cnt = cntS[w];

    float2 acc = bf2f(hnb[(size_t)w * 64 + lane]);   // self loop

    for (int j0 = 0; j0 < cnt; j0 += 64) {
        const int m = min(64, cnt - j0);
        int dl = 0;
        if (lane < m) dl = eDst[beg + j0 + lane];    // one coalesced load per 64 nbrs
        int q = 0;
#pragma unroll 1
        for (; q + 8 <= m; q += 8) {
            const int d0 = __shfl(dl, q + 0);
            const int d1 = __shfl(dl, q + 1);
            const int d2 = __shfl(dl, q + 2);
            const int d3 = __shfl(dl, q + 3);
            const int d4 = __shfl(dl, q + 4);
            const int d5 = __shfl(dl, q + 5);
            const int d6 = __shfl(dl, q + 6);
            const int d7 = __shfl(dl, q + 7);
            const unsigned v0 = hnb[(size_t)d0 * 64 + lane];
            const unsigned v1 = hnb[(size_t)d1 * 64 + lane];
            const unsigned v2 = hnb[(size_t)d2 * 64 + lane];
            const unsigned v3 = hnb[(size_t)d3 * 64 + lane];
            const unsigned v4 = hnb[(size_t)d4 * 64 + lane];
            const unsigned v5 = hnb[(size_t)d5 * 64 + lane];
            const unsigned v6 = hnb[(size_t)d6 * 64 + lane];
            const unsigned v7 = hnb[(size_t)d7 * 64 + lane];
            float2 a = bf2f(v0), b = bf2f(v1), c = bf2f(v2), d = bf2f(v3);
            float2 e = bf2f(v4), f = bf2f(v5), g = bf2f(v6), h = bf2f(v7);
            acc.x += ((a.x + b.x) + (c.x + d.x)) + ((e.x + f.x) + (g.x + h.x));
            acc.y += ((a.y + b.y) + (c.y + d.y)) + ((e.y + f.y) + (g.y + h.y));
        }
        for (; q < m; ++q) {
            const int d = __shfl(dl, q);
            const float2 v = bf2f(hnb[(size_t)d * 64 + lane]);
            acc.x += v.x; acc.y += v.y;
        }
    }
    const float s = invd[w];
    *(float2*)(out + (size_t)w * C + lane * 2) = make_float2(acc.x * s, acc.y * s);
}

extern "C" void kernel_launch(void* const* d_in, const int* in_sizes, int n_in,
                              void* d_out, int out_size, void* d_ws, size_t ws_size,
                              hipStream_t stream) {
    const float* x = (const float*)d_in[0];
    const void* edges = d_in[1];
    const float* W = (const float*)d_in[2];
    float* out = (float*)d_out;

    const int N = in_sizes[0] / C;
    const long long E = (long long)in_sizes[1] / 2;

    char* ws = (char*)d_ws;
    int*      flagp = (int*)(ws + OFF_FLAG);
    int*      degD  = (int*)(ws + OFF_DEGD);
    int*      cntS  = (int*)(ws + OFF_CNTS);
    float*    invd  = (float*)(ws + OFF_INVD);
    int*      offS  = (int*)(ws + OFF_OFFS);
    int*      cur   = (int*)(ws + OFF_CUR);
    int*      bsum  = (int*)(ws + OFF_BSUM);
    int*      eDst  = (int*)(ws + OFF_EDST);
    unsigned short* hn = (unsigned short*)(ws + OFF_HN);

    const int nBlkN = (N + TPB - 1) / TPB;                  // 391
    const int nBlkE = (int)((E + TPB - 1) / TPB);           // 6250

    int nCheck = (int)(E < 4096 ? E : 4096);
    detect_kernel<<<1, TPB, 0, stream>>>((const unsigned int*)edges, nCheck, flagp);
    zero2_kernel<<<nBlkN, TPB, 0, stream>>>(degD, cntS, N);
    count_kernel<<<nBlkE, TPB, 0, stream>>>(edges, flagp, E, degD, cntS);
    invd_kernel<<<nBlkN, TPB, 0, stream>>>(degD, invd, N);
    scan1_kernel<<<nBlkN, TPB, 0, stream>>>(cntS, offS, bsum, N);
    scan2_kernel<<<1, 512, 0, stream>>>(bsum, nBlkN);
    scan3_kernel<<<nBlkN, TPB, 0, stream>>>(offS, bsum, cur, N);
    fill_kernel<<<nBlkE, TPB, 0, stream>>>(edges, flagp, E, cur, eDst);

    const int nBlkG = (N + BM - 1) / BM;                    // 782
    gemm_hn_kernel<<<nBlkG, TPB, 0, stream>>>(x, W, invd, hn, N);

    const int nBlkA = (N * 64 + TPB - 1) / TPB;             // 25000 (wave per node)
    gather_kernel<<<nBlkA, TPB, 0, stream>>>(offS, cntS, eDst, (const unsigned*)hn,
                                             invd, out, N);
}

// Round 5
// 362.311 us; speedup vs baseline: 4.2086x; 1.2969x over previous
//
#include <hip/hip_runtime.h>
#include <hip/hip_bf16.h>

#define C 128            // C_IN == C_OUT == 128
#define TPB 256

typedef __attribute__((ext_vector_type(8))) _Float16 half8;
typedef __attribute__((ext_vector_type(4))) float f32x4;

// ---------------- workspace layout (bytes) ----------------
#define OFF_FLAG 0x0
#define OFF_DEGD 0x400       // int[N]   in-degree (by dst)
#define OFF_CNTS 0x80000     // int[N]   out-degree (by src)
#define OFF_INVD 0x100000    // float[N] 1/(degD+1)
#define OFF_OFFS 0x180000    // int[N]   CSR row offsets (exclusive scan of cntS)
#define OFF_CUR  0x200000    // int[N]   fill cursors (init = offS)
#define OFF_BSUM 0x280000    // int[512] scan partials
#define OFF_W16  0x290000    // f16[128*128] W in fp16 (32 KB)
#define OFF_EDST 0x300000    // int[E]   CSR adjacency (dst per slot)
#define OFF_HN   0xA00000    // bf16[N*128] hn = (x@W^T) * invd

__device__ __forceinline__ unsigned f2bf_bits(float f) {
    unsigned u = __float_as_uint(f);
    return (u + 0x7fffu + ((u >> 16) & 1u)) >> 16;   // RNE
}
__device__ __forceinline__ float2 bf2f(unsigned u) {
    return make_float2(__uint_as_float(u << 16), __uint_as_float(u & 0xffff0000u));
}

// Detect whether edge_index is int64 (high 32-bit words all zero) or int32.
__global__ void detect_kernel(const unsigned int* __restrict__ ew, int nCheck,
                              int* __restrict__ flagp) {
    __shared__ int s;
    if (threadIdx.x == 0) s = 0;
    __syncthreads();
    int any = 0;
    for (int i = threadIdx.x; i < nCheck; i += TPB)
        any |= (ew[2 * i + 1] != 0u);
    if (any) s = 1;              // some high word nonzero -> int32 layout
    __syncthreads();
    if (threadIdx.x == 0) *flagp = s;
}

__device__ __forceinline__ void load_edge(const void* edges, long long E, int is32,
                                          long long e, int& s, int& d) {
    if (is32) {
        const int* p = (const int*)edges;
        s = p[e]; d = p[E + e];
    } else {
        const long long* p = (const long long*)edges;
        s = (int)p[e]; d = (int)p[E + e];
    }
}

__global__ void zero2_kernel(int* degD, int* cntS, int N) {
    int i = blockIdx.x * TPB + threadIdx.x;
    if (i < N) { degD[i] = 0; cntS[i] = 0; }
}

__global__ void count_kernel(const void* __restrict__ edges, const int* __restrict__ flagp,
                             long long E, int* __restrict__ degD, int* __restrict__ cntS) {
    long long e = (long long)blockIdx.x * TPB + threadIdx.x;
    if (e >= E) return;
    int s, d;
    load_edge(edges, E, *flagp, e, s, d);
    atomicAdd(&degD[d], 1);
    atomicAdd(&cntS[s], 1);
}

// W (f32, [128][128]) -> fp16
__global__ void wprep_kernel(const float* __restrict__ W, _Float16* __restrict__ W16) {
    int i = blockIdx.x * TPB + threadIdx.x;   // 16384 total
    W16[i] = (_Float16)W[i];
}

// exclusive scan of cntS -> offS ; per-block totals -> bsum
__global__ __launch_bounds__(TPB) void scan1_kernel(const int* __restrict__ cntS,
                                                    int* __restrict__ offS,
                                                    int* __restrict__ bsum, int N) {
    __shared__ int s[TPB];
    const int t = threadIdx.x;
    const int i = blockIdx.x * TPB + t;
    int v = (i < N) ? cntS[i] : 0;
    s[t] = v;
    __syncthreads();
    for (int d = 1; d < TPB; d <<= 1) {
        int add = (t >= d) ? s[t - d] : 0;
        __syncthreads();
        s[t] += add;
        __syncthreads();
    }
    if (i < N) offS[i] = s[t] - v;                 // local exclusive
    if (t == TPB - 1) bsum[blockIdx.x] = s[t];     // block total
}

__global__ void scan2_kernel(int* __restrict__ bsum, int nb) {
    __shared__ int s[512];
    const int t = threadIdx.x;   // 512 threads
    int v = (t < nb) ? bsum[t] : 0;
    s[t] = v;
    __syncthreads();
    for (int d = 1; d < 512; d <<= 1) {
        int add = (t >= d) ? s[t - d] : 0;
        __syncthreads();
        s[t] += add;
        __syncthreads();
    }
    if (t < nb) bsum[t] = s[t] - v;                // exclusive
}

// finalize offsets, init cursors, and compute invd = 1/(degD+1) (fused)
__global__ void scan3_kernel(int* __restrict__ offS, const int* __restrict__ bsum,
                             int* __restrict__ cur, const int* __restrict__ degD,
                             float* __restrict__ invd, int N) {
    int i = blockIdx.x * TPB + threadIdx.x;
    if (i < N) {
        int v = offS[i] + bsum[blockIdx.x];
        offS[i] = v;
        cur[i] = v;                                // cursor starts at row offset
        invd[i] = 1.0f / (float)(degD[i] + 1);
    }
}

__global__ void fill_kernel(const void* __restrict__ edges, const int* __restrict__ flagp,
                            long long E, int* __restrict__ cur, int* __restrict__ eDst) {
    long long e = (long long)blockIdx.x * TPB + threadIdx.x;
    if (e >= E) return;
    int s, d;
    load_edge(edges, E, *flagp, e, s, d);
    int pos = atomicAdd(&cur[s], 1);
    eDst[pos] = d;
}

// hn[i][:] = bf16( (x[i] @ W^T) * invd[i] )  via mfma_f32_16x16x32_f16.
// No LDS. Each wave computes a 32x128 strip (2 m-blocks x 8 n-frags).
// A-frag: lane holds x[m0+mb*16+(l&15)][ks*32+(l>>4)*8 ..+7] (f32->f16 in reg).
// B-frag: lane holds W16[nf*16+(l&15)][ks*32+(l>>4)*8 ..+7] (16B load; W16 is
// 32 KB -> L1-resident).
// C/D: col = lane&15, row = (lane>>4)*4 + reg  [m89-verified, dtype-indep].
__global__ __launch_bounds__(TPB) void gemm_mfma_kernel(const float* __restrict__ x,
                                                        const _Float16* __restrict__ W16,
                                                        const float* __restrict__ invd,
                                                        unsigned short* __restrict__ hn,
                                                        int N) {
    const int t = threadIdx.x;
    const int lane = t & 63;
    const int wid = t >> 6;
    const int lr = lane & 15;      // row (A) / col (B) within fragment
    const int lk = lane >> 4;      // k-block (0..3)
    const int m0 = blockIdx.x * 128 + wid * 32;

    // ---- A fragments: 2 m-blocks x 4 k-steps ----
    half8 a[2][4];
#pragma unroll
    for (int mb = 0; mb < 2; ++mb) {
        const int row = m0 + mb * 16 + lr;
        const float* xp = x + (size_t)row * C + lk * 8;
#pragma unroll
        for (int ks = 0; ks < 4; ++ks) {
            half8 av;
            if (row < N) {
                const float4 v0 = *(const float4*)(xp + ks * 32);
                const float4 v1 = *(const float4*)(xp + ks * 32 + 4);
                av[0] = (_Float16)v0.x; av[1] = (_Float16)v0.y;
                av[2] = (_Float16)v0.z; av[3] = (_Float16)v0.w;
                av[4] = (_Float16)v1.x; av[5] = (_Float16)v1.y;
                av[6] = (_Float16)v1.z; av[7] = (_Float16)v1.w;
            } else {
                av = (half8)((_Float16)0.f);
            }
            a[mb][ks] = av;
        }
    }

    f32x4 acc[2][8];
#pragma unroll
    for (int mb = 0; mb < 2; ++mb)
#pragma unroll
        for (int nf = 0; nf < 8; ++nf)
            acc[mb][nf] = (f32x4){0.f, 0.f, 0.f, 0.f};

#pragma unroll
    for (int nf = 0; nf < 8; ++nf) {
        half8 b[4];
        const _Float16* wp = W16 + (size_t)(nf * 16 + lr) * C + lk * 8;
#pragma unroll
        for (int ks = 0; ks < 4; ++ks)
            b[ks] = *(const half8*)(wp + ks * 32);
#pragma unroll
        for (int mb = 0; mb < 2; ++mb)
#pragma unroll
            for (int ks = 0; ks < 4; ++ks)
                acc[mb][nf] = __builtin_amdgcn_mfma_f32_16x16x32_f16(
                    a[mb][ks], b[ks], acc[mb][nf], 0, 0, 0);
    }

    // ---- epilogue: scale by invd, pack bf16, store ----
#pragma unroll
    for (int mb = 0; mb < 2; ++mb) {
#pragma unroll
        for (int r = 0; r < 4; ++r) {
            const int row = m0 + mb * 16 + lk * 4 + r;
            if (row < N) {
                const float idv = invd[row];
                unsigned short* hp = hn + (size_t)row * C + lr;
#pragma unroll
                for (int nf = 0; nf < 8; ++nf)
                    hp[nf * 16] = (unsigned short)f2bf_bits(acc[mb][nf][r] * idv);
            }
        }
    }
}

// One wave per node: out[i] = (sum_{j in adj[i]} hn[j] + hn[i]) * invd[i]
// hn rows are 128 bf16 = 64 lanes x 1 dword, fully coalesced 256B per row.
__global__ __launch_bounds__(TPB) void gather_kernel(const int* __restrict__ offS,
                                                     const int* __restrict__ cntS,
                                                     const int* __restrict__ eDst,
                                                     const unsigned* __restrict__ hnb,
                                                     const float* __restrict__ invd,
                                                     float* __restrict__ out, int N) {
    const int lane = threadIdx.x & 63;
    const int w = (blockIdx.x * TPB + threadIdx.x) >> 6;
    if (w >= N) return;
    const int beg = offS[w];
    const int cnt = cntS[w];

    float2 acc = bf2f(hnb[(size_t)w * 64 + lane]);   // self loop

    for (int j0 = 0; j0 < cnt; j0 += 64) {
        const int m = min(64, cnt - j0);
        int dl = 0;
        if (lane < m) dl = eDst[beg + j0 + lane];    // one coalesced load per 64 nbrs
        int q = 0;
#pragma unroll 1
        for (; q + 8 <= m; q += 8) {
            const int d0 = __shfl(dl, q + 0);
            const int d1 = __shfl(dl, q + 1);
            const int d2 = __shfl(dl, q + 2);
            const int d3 = __shfl(dl, q + 3);
            const int d4 = __shfl(dl, q + 4);
            const int d5 = __shfl(dl, q + 5);
            const int d6 = __shfl(dl, q + 6);
            const int d7 = __shfl(dl, q + 7);
            const unsigned v0 = hnb[(size_t)d0 * 64 + lane];
            const unsigned v1 = hnb[(size_t)d1 * 64 + lane];
            const unsigned v2 = hnb[(size_t)d2 * 64 + lane];
            const unsigned v3 = hnb[(size_t)d3 * 64 + lane];
            const unsigned v4 = hnb[(size_t)d4 * 64 + lane];
            const unsigned v5 = hnb[(size_t)d5 * 64 + lane];
            const unsigned v6 = hnb[(size_t)d6 * 64 + lane];
            const unsigned v7 = hnb[(size_t)d7 * 64 + lane];
            float2 a = bf2f(v0), b = bf2f(v1), c = bf2f(v2), d = bf2f(v3);
            float2 e = bf2f(v4), f = bf2f(v5), g = bf2f(v6), h = bf2f(v7);
            acc.x += ((a.x + b.x) + (c.x + d.x)) + ((e.x + f.x) + (g.x + h.x));
            acc.y += ((a.y + b.y) + (c.y + d.y)) + ((e.y + f.y) + (g.y + h.y));
        }
        for (; q < m; ++q) {
            const int d = __shfl(dl, q);
            const float2 v = bf2f(hnb[(size_t)d * 64 + lane]);
            acc.x += v.x; acc.y += v.y;
        }
    }
    const float s = invd[w];
    *(float2*)(out + (size_t)w * C + lane * 2) = make_float2(acc.x * s, acc.y * s);
}

extern "C" void kernel_launch(void* const* d_in, const int* in_sizes, int n_in,
                              void* d_out, int out_size, void* d_ws, size_t ws_size,
                              hipStream_t stream) {
    const float* x = (const float*)d_in[0];
    const void* edges = d_in[1];
    const float* W = (const float*)d_in[2];
    float* out = (float*)d_out;

    const int N = in_sizes[0] / C;
    const long long E = (long long)in_sizes[1] / 2;

    char* ws = (char*)d_ws;
    int*       flagp = (int*)(ws + OFF_FLAG);
    int*       degD  = (int*)(ws + OFF_DEGD);
    int*       cntS  = (int*)(ws + OFF_CNTS);
    float*     invd  = (float*)(ws + OFF_INVD);
    int*       offS  = (int*)(ws + OFF_OFFS);
    int*       cur   = (int*)(ws + OFF_CUR);
    int*       bsum  = (int*)(ws + OFF_BSUM);
    _Float16*  W16   = (_Float16*)(ws + OFF_W16);
    int*       eDst  = (int*)(ws + OFF_EDST);
    unsigned short* hn = (unsigned short*)(ws + OFF_HN);

    const int nBlkN = (N + TPB - 1) / TPB;                  // 391
    const int nBlkE = (int)((E + TPB - 1) / TPB);           // 6250

    int nCheck = (int)(E < 4096 ? E : 4096);
    detect_kernel<<<1, TPB, 0, stream>>>((const unsigned int*)edges, nCheck, flagp);
    zero2_kernel<<<nBlkN, TPB, 0, stream>>>(degD, cntS, N);
    wprep_kernel<<<(C * C) / TPB, TPB, 0, stream>>>(W, W16);
    count_kernel<<<nBlkE, TPB, 0, stream>>>(edges, flagp, E, degD, cntS);
    scan1_kernel<<<nBlkN, TPB, 0, stream>>>(cntS, offS, bsum, N);
    scan2_kernel<<<1, 512, 0, stream>>>(bsum, nBlkN);
    scan3_kernel<<<nBlkN, TPB, 0, stream>>>(offS, bsum, cur, degD, invd, N);
    fill_kernel<<<nBlkE, TPB, 0, stream>>>(edges, flagp, E, cur, eDst);

    const int nBlkG = (N + 127) / 128;                      // 782 (4 waves x 32 rows)
    gemm_mfma_kernel<<<nBlkG, TPB, 0, stream>>>(x, W16, invd, hn, N);

    const int nBlkA = (N * 64 + TPB - 1) / TPB;             // 25000 (wave per node)
    gather_kernel<<<nBlkA, TPB, 0, stream>>>(offS, cntS, eDst, (const unsigned*)hn,
                                             invd, out, N);
}

// Round 6
// 335.964 us; speedup vs baseline: 4.5386x; 1.0784x over previous
//
#include <hip/hip_runtime.h>
#include <hip/hip_bf16.h>

#define C 128            // C_IN == C_OUT == 128
#define TPB 256
#define NPASS 4          // fill src-range passes (eDst region/pass ~1.6MB -> L2-resident)

typedef __attribute__((ext_vector_type(8))) _Float16 half8;
typedef __attribute__((ext_vector_type(4))) float f32x4;

// ---------------- workspace layout (bytes) ----------------
#define OFF_FLAG 0x0
#define OFF_DEGD 0x400       // int[N]   in-degree (by dst)
#define OFF_CNTS 0x80000     // int[N]   out-degree (by src)
#define OFF_INVD 0x100000    // float[N] 1/(degD+1)
#define OFF_OFFS 0x180000    // int[N]   CSR row offsets (exclusive scan of cntS)
#define OFF_CUR  0x200000    // int[N]   fill cursors (init = offS)
#define OFF_BSUM 0x280000    // int[512] scan partials
#define OFF_W16  0x290000    // f16[128*128] W in fp16 (32 KB)
#define OFF_EDST 0x300000    // int[E]   CSR adjacency (dst per slot)
#define OFF_HN   0xA00000    // bf16[N*128] hn = (x@W^T) * invd
// src32/dst32 (int[E] each) live in d_out: dead before gather rewrites out fully.

__device__ __forceinline__ unsigned f2bf_bits(float f) {
    unsigned u = __float_as_uint(f);
    return (u + 0x7fffu + ((u >> 16) & 1u)) >> 16;   // RNE
}
__device__ __forceinline__ float2 bf2f(unsigned u) {
    return make_float2(__uint_as_float(u << 16), __uint_as_float(u & 0xffff0000u));
}

// Detect whether edge_index is int64 (high 32-bit words all zero) or int32.
__global__ void detect_kernel(const unsigned int* __restrict__ ew, int nCheck,
                              int* __restrict__ flagp) {
    __shared__ int s;
    if (threadIdx.x == 0) s = 0;
    __syncthreads();
    int any = 0;
    for (int i = threadIdx.x; i < nCheck; i += TPB)
        any |= (ew[2 * i + 1] != 0u);
    if (any) s = 1;              // some high word nonzero -> int32 layout
    __syncthreads();
    if (threadIdx.x == 0) *flagp = s;
}

__global__ void zero2_kernel(int* degD, int* cntS, int N) {
    int i = blockIdx.x * TPB + threadIdx.x;
    if (i < N) { degD[i] = 0; cntS[i] = 0; }
}

// Decode edges (int64 or int32) -> src32/dst32, and count both degrees.
__global__ void convcnt_kernel(const void* __restrict__ edges,
                               const int* __restrict__ flagp, long long E,
                               int* __restrict__ src32, int* __restrict__ dst32,
                               int* __restrict__ degD, int* __restrict__ cntS) {
    long long e = (long long)blockIdx.x * TPB + threadIdx.x;
    if (e >= E) return;
    int s, d;
    if (*flagp) {                       // int32 layout
        const int* p = (const int*)edges;
        s = p[e]; d = p[E + e];
    } else {                            // int64 layout
        const long long* p = (const long long*)edges;
        s = (int)p[e]; d = (int)p[E + e];
    }
    src32[e] = s;
    dst32[e] = d;
    atomicAdd(&degD[d], 1);
    atomicAdd(&cntS[s], 1);
}

// W (f32, [128][128]) -> fp16
__global__ void wprep_kernel(const float* __restrict__ W, _Float16* __restrict__ W16) {
    int i = blockIdx.x * TPB + threadIdx.x;   // 16384 total
    W16[i] = (_Float16)W[i];
}

// exclusive scan of cntS -> offS ; per-block totals -> bsum
__global__ __launch_bounds__(TPB) void scan1_kernel(const int* __restrict__ cntS,
                                                    int* __restrict__ offS,
                                                    int* __restrict__ bsum, int N) {
    __shared__ int s[TPB];
    const int t = threadIdx.x;
    const int i = blockIdx.x * TPB + t;
    int v = (i < N) ? cntS[i] : 0;
    s[t] = v;
    __syncthreads();
    for (int d = 1; d < TPB; d <<= 1) {
        int add = (t >= d) ? s[t - d] : 0;
        __syncthreads();
        s[t] += add;
        __syncthreads();
    }
    if (i < N) offS[i] = s[t] - v;                 // local exclusive
    if (t == TPB - 1) bsum[blockIdx.x] = s[t];     // block total
}

__global__ void scan2_kernel(int* __restrict__ bsum, int nb) {
    __shared__ int s[512];
    const int t = threadIdx.x;   // 512 threads
    int v = (t < nb) ? bsum[t] : 0;
    s[t] = v;
    __syncthreads();
    for (int d = 1; d < 512; d <<= 1) {
        int add = (t >= d) ? s[t - d] : 0;
        __syncthreads();
        s[t] += add;
        __syncthreads();
    }
    if (t < nb) bsum[t] = s[t] - v;                // exclusive
}

// finalize offsets, init cursors, and compute invd = 1/(degD+1) (fused)
__global__ void scan3_kernel(int* __restrict__ offS, const int* __restrict__ bsum,
                             int* __restrict__ cur, const int* __restrict__ degD,
                             float* __restrict__ invd, int N) {
    int i = blockIdx.x * TPB + threadIdx.x;
    if (i < N) {
        int v = offS[i] + bsum[blockIdx.x];
        offS[i] = v;
        cur[i] = v;                                // cursor starts at row offset
        invd[i] = 1.0f / (float)(degD[i] + 1);
    }
}

// Place edges with src in [lo,hi). Target eDst region is ~E/NPASS*4B,
// L2-resident -> full-line writebacks instead of 64B-per-4B-store.
__global__ void fill_range_kernel(const int* __restrict__ src32,
                                  const int* __restrict__ dst32, long long E,
                                  int* __restrict__ cur, int* __restrict__ eDst,
                                  int lo, int hi) {
    long long e = (long long)blockIdx.x * TPB + threadIdx.x;
    if (e >= E) return;
    const int s = src32[e];
    if (s < lo || s >= hi) return;
    const int d = dst32[e];
    int pos = atomicAdd(&cur[s], 1);
    eDst[pos] = d;
}

// hn[i][:] = bf16( (x[i] @ W^T) * invd[i] )  via mfma_f32_16x16x32_f16.
// No LDS. Each wave computes a 32x128 strip (2 m-blocks x 8 n-frags).
__global__ __launch_bounds__(TPB) void gemm_mfma_kernel(const float* __restrict__ x,
                                                        const _Float16* __restrict__ W16,
                                                        const float* __restrict__ invd,
                                                        unsigned short* __restrict__ hn,
                                                        int N) {
    const int t = threadIdx.x;
    const int lane = t & 63;
    const int wid = t >> 6;
    const int lr = lane & 15;      // row (A) / col (B) within fragment
    const int lk = lane >> 4;      // k-block (0..3)
    const int m0 = blockIdx.x * 128 + wid * 32;

    // ---- A fragments: 2 m-blocks x 4 k-steps ----
    half8 a[2][4];
#pragma unroll
    for (int mb = 0; mb < 2; ++mb) {
        const int row = m0 + mb * 16 + lr;
        const float* xp = x + (size_t)row * C + lk * 8;
#pragma unroll
        for (int ks = 0; ks < 4; ++ks) {
            half8 av;
            if (row < N) {
                const float4 v0 = *(const float4*)(xp + ks * 32);
                const float4 v1 = *(const float4*)(xp + ks * 32 + 4);
                av[0] = (_Float16)v0.x; av[1] = (_Float16)v0.y;
                av[2] = (_Float16)v0.z; av[3] = (_Float16)v0.w;
                av[4] = (_Float16)v1.x; av[5] = (_Float16)v1.y;
                av[6] = (_Float16)v1.z; av[7] = (_Float16)v1.w;
            } else {
                av = (half8)((_Float16)0.f);
            }
            a[mb][ks] = av;
        }
    }

    f32x4 acc[2][8];
#pragma unroll
    for (int mb = 0; mb < 2; ++mb)
#pragma unroll
        for (int nf = 0; nf < 8; ++nf)
            acc[mb][nf] = (f32x4){0.f, 0.f, 0.f, 0.f};

#pragma unroll
    for (int nf = 0; nf < 8; ++nf) {
        half8 b[4];
        const _Float16* wp = W16 + (size_t)(nf * 16 + lr) * C + lk * 8;
#pragma unroll
        for (int ks = 0; ks < 4; ++ks)
            b[ks] = *(const half8*)(wp + ks * 32);
#pragma unroll
        for (int mb = 0; mb < 2; ++mb)
#pragma unroll
            for (int ks = 0; ks < 4; ++ks)
                acc[mb][nf] = __builtin_amdgcn_mfma_f32_16x16x32_f16(
                    a[mb][ks], b[ks], acc[mb][nf], 0, 0, 0);
    }

    // ---- epilogue: scale by invd, pack bf16, store ----
#pragma unroll
    for (int mb = 0; mb < 2; ++mb) {
#pragma unroll
        for (int r = 0; r < 4; ++r) {
            const int row = m0 + mb * 16 + lk * 4 + r;
            if (row < N) {
                const float idv = invd[row];
                unsigned short* hp = hn + (size_t)row * C + lr;
#pragma unroll
                for (int nf = 0; nf < 8; ++nf)
                    hp[nf * 16] = (unsigned short)f2bf_bits(acc[mb][nf][r] * idv);
            }
        }
    }
}

// One wave per node: out[i] = (sum_{j in adj[i]} hn[j] + hn[i]) * invd[i]
__global__ __launch_bounds__(TPB) void gather_kernel(const int* __restrict__ offS,
                                                     const int* __restrict__ cntS,
                                                     const int* __restrict__ eDst,
                                                     const unsigned* __restrict__ hnb,
                                                     const float* __restrict__ invd,
                                                     float* __restrict__ out, int N) {
    const int lane = threadIdx.x & 63;
    const int w = (blockIdx.x * TPB + threadIdx.x) >> 6;
    if (w >= N) return;
    const int beg = offS[w];
    const int cnt = cntS[w];

    float2 acc = bf2f(hnb[(size_t)w * 64 + lane]);   // self loop

    for (int j0 = 0; j0 < cnt; j0 += 64) {
        const int m = min(64, cnt - j0);
        int dl = 0;
        if (lane < m) dl = eDst[beg + j0 + lane];    // one coalesced load per 64 nbrs
        int q = 0;
#pragma unroll 1
        for (; q + 8 <= m; q += 8) {
            const int d0 = __shfl(dl, q + 0);
            const int d1 = __shfl(dl, q + 1);
            const int d2 = __shfl(dl, q + 2);
            const int d3 = __shfl(dl, q + 3);
            const int d4 = __shfl(dl, q + 4);
            const int d5 = __shfl(dl, q + 5);
            const int d6 = __shfl(dl, q + 6);
            const int d7 = __shfl(dl, q + 7);
            const unsigned v0 = hnb[(size_t)d0 * 64 + lane];
            const unsigned v1 = hnb[(size_t)d1 * 64 + lane];
            const unsigned v2 = hnb[(size_t)d2 * 64 + lane];
            const unsigned v3 = hnb[(size_t)d3 * 64 + lane];
            const unsigned v4 = hnb[(size_t)d4 * 64 + lane];
            const unsigned v5 = hnb[(size_t)d5 * 64 + lane];
            const unsigned v6 = hnb[(size_t)d6 * 64 + lane];
            const unsigned v7 = hnb[(size_t)d7 * 64 + lane];
            float2 a = bf2f(v0), b = bf2f(v1), c = bf2f(v2), d = bf2f(v3);
            float2 e = bf2f(v4), f = bf2f(v5), g = bf2f(v6), h = bf2f(v7);
            acc.x += ((a.x + b.x) + (c.x + d.x)) + ((e.x + f.x) + (g.x + h.x));
            acc.y += ((a.y + b.y) + (c.y + d.y)) + ((e.y + f.y) + (g.y + h.y));
        }
        for (; q < m; ++q) {
            const int d = __shfl(dl, q);
            const float2 v = bf2f(hnb[(size_t)d * 64 + lane]);
            acc.x += v.x; acc.y += v.y;
        }
    }
    const float s = invd[w];
    *(float2*)(out + (size_t)w * C + lane * 2) = make_float2(acc.x * s, acc.y * s);
}

extern "C" void kernel_launch(void* const* d_in, const int* in_sizes, int n_in,
                              void* d_out, int out_size, void* d_ws, size_t ws_size,
                              hipStream_t stream) {
    const float* x = (const float*)d_in[0];
    const void* edges = d_in[1];
    const float* W = (const float*)d_in[2];
    float* out = (float*)d_out;

    const int N = in_sizes[0] / C;
    const long long E = (long long)in_sizes[1] / 2;

    char* ws = (char*)d_ws;
    int*       flagp = (int*)(ws + OFF_FLAG);
    int*       degD  = (int*)(ws + OFF_DEGD);
    int*       cntS  = (int*)(ws + OFF_CNTS);
    float*     invd  = (float*)(ws + OFF_INVD);
    int*       offS  = (int*)(ws + OFF_OFFS);
    int*       cur   = (int*)(ws + OFF_CUR);
    int*       bsum  = (int*)(ws + OFF_BSUM);
    _Float16*  W16   = (_Float16*)(ws + OFF_W16);
    int*       eDst  = (int*)(ws + OFF_EDST);
    unsigned short* hn = (unsigned short*)(ws + OFF_HN);

    // src32/dst32 staged in d_out (dead until gather fully rewrites out)
    int* src32 = (int*)d_out;
    int* dst32 = (int*)d_out + E;

    const int nBlkN = (N + TPB - 1) / TPB;                  // 391
    const int nBlkE = (int)((E + TPB - 1) / TPB);           // 6250

    int nCheck = (int)(E < 4096 ? E : 4096);
    detect_kernel<<<1, TPB, 0, stream>>>((const unsigned int*)edges, nCheck, flagp);
    zero2_kernel<<<nBlkN, TPB, 0, stream>>>(degD, cntS, N);
    wprep_kernel<<<(C * C) / TPB, TPB, 0, stream>>>(W, W16);
    convcnt_kernel<<<nBlkE, TPB, 0, stream>>>(edges, flagp, E, src32, dst32, degD, cntS);
    scan1_kernel<<<nBlkN, TPB, 0, stream>>>(cntS, offS, bsum, N);
    scan2_kernel<<<1, 512, 0, stream>>>(bsum, nBlkN);
    scan3_kernel<<<nBlkN, TPB, 0, stream>>>(offS, bsum, cur, degD, invd, N);

    for (int p = 0; p < NPASS; ++p) {
        int lo = (int)((long long)N * p / NPASS);
        int hi = (int)((long long)N * (p + 1) / NPASS);
        fill_range_kernel<<<nBlkE, TPB, 0, stream>>>(src32, dst32, E, cur, eDst, lo, hi);
    }

    const int nBlkG = (N + 127) / 128;                      // 782 (4 waves x 32 rows)
    gemm_mfma_kernel<<<nBlkG, TPB, 0, stream>>>(x, W16, invd, hn, N);

    const int nBlkA = (N * 64 + TPB - 1) / TPB;             // 25000 (wave per node)
    gather_kernel<<<nBlkA, TPB, 0, stream>>>(offS, cntS, eDst, (const unsigned*)hn,
                                             invd, out, N);
}

// Round 7
// 258.015 us; speedup vs baseline: 5.9098x; 1.3021x over previous
//
#include <hip/hip_runtime.h>
#include <hip/hip_bf16.h>

#define C 128            // C_IN == C_OUT == 128
#define TPB 256
#define BWID 512         // nodes per coarse bucket (bucket = node >> 9)
#define NBUK 256         // max buckets: supports N <= 131072

typedef __attribute__((ext_vector_type(8))) _Float16 half8;
typedef __attribute__((ext_vector_type(4))) float f32x4;
typedef unsigned long long u64;

// ---------------- workspace layout (bytes) ----------------
#define OFF_FLAG  0x0        // int      edge-dtype flag
#define OFF_BSS   0x400      // int[257] bucket edge-starts (src partition)
#define OFF_BSD   0xC00      // int[257] bucket edge-starts (dst partition)
#define OFF_HISTS 0x10000    // int[256*256] per-(block,bucket) src counts -> base offsets
#define OFF_HISTD 0x50000    // int[256*256] same for dst
#define OFF_OFFS  0xA0000    // int[N]   CSR row offsets
#define OFF_CNTS  0x110000   // int[N]   out-degree
#define OFF_INVD  0x180000   // float[N] 1/(in-degree+1)
#define OFF_W16   0x1F0000   // f16[128*128] W (32 KB)
#define OFF_EDST  0x200000   // int[E]   CSR adjacency
#define OFF_HN    0x900000   // bf16[N*128] hn = (x@W^T) * invd
// d_out staging (dead until gather rewrites out): src32[E], dst32[E],
// partS u64[E] (src,dst pairs partitioned by src), partD int[E] (dst values
// partitioned by dst). 7E ints = 44.8 MB <= out 51.2 MB.

__device__ __forceinline__ unsigned f2bf_bits(float f) {
    unsigned u = __float_as_uint(f);
    return (u + 0x7fffu + ((u >> 16) & 1u)) >> 16;   // RNE
}
__device__ __forceinline__ float2 bf2f(unsigned u) {
    return make_float2(__uint_as_float(u << 16), __uint_as_float(u & 0xffff0000u));
}

// Detect whether edge_index is int64 (high 32-bit words all zero) or int32.
__global__ void detect_kernel(const unsigned int* __restrict__ ew, int nCheck,
                              int* __restrict__ flagp) {
    __shared__ int s;
    if (threadIdx.x == 0) s = 0;
    __syncthreads();
    int any = 0;
    for (int i = threadIdx.x; i < nCheck; i += TPB)
        any |= (ew[2 * i + 1] != 0u);
    if (any) s = 1;              // some high word nonzero -> int32 layout
    __syncthreads();
    if (threadIdx.x == 0) *flagp = s;
}

// Decode edges (int64 or int32) -> src32/dst32. No atomics.
__global__ void conv_kernel(const void* __restrict__ edges,
                            const int* __restrict__ flagp, long long E,
                            int* __restrict__ src32, int* __restrict__ dst32) {
    long long e = (long long)blockIdx.x * TPB + threadIdx.x;
    if (e >= E) return;
    int s, d;
    if (*flagp) {
        const int* p = (const int*)edges;
        s = p[e]; d = p[E + e];
    } else {
        const long long* p = (const long long*)edges;
        s = (int)p[e]; d = (int)p[E + e];
    }
    src32[e] = s;
    dst32[e] = d;
}

// Per-block LDS histograms over coarse buckets, for src and dst streams.
__global__ __launch_bounds__(TPB) void hist_kernel(const int* __restrict__ src32,
                                                   const int* __restrict__ dst32,
                                                   long long E, int chunk,
                                                   int* __restrict__ histS,
                                                   int* __restrict__ histD) {
    __shared__ int hs[NBUK], hd[NBUK];
    const int t = threadIdx.x;
    hs[t] = 0; hd[t] = 0;                      // TPB == NBUK
    __syncthreads();
    const long long b0 = (long long)blockIdx.x * chunk;
    for (int i = t; i < chunk; i += TPB) {
        const long long e = b0 + i;
        if (e < E) {
            atomicAdd(&hs[src32[e] >> 9], 1);  // LDS atomic
            atomicAdd(&hd[dst32[e] >> 9], 1);
        }
    }
    __syncthreads();
    histS[blockIdx.x * NBUK + t] = hs[t];
    histD[blockIdx.x * NBUK + t] = hd[t];
}

// In-place hist -> global base offsets; bucket edge-starts with sentinel.
// block 0: src partition, block 1: dst partition.
__global__ __launch_bounds__(TPB) void scanbase_kernel(int* __restrict__ histS,
                                                       int* __restrict__ histD,
                                                       int* __restrict__ bsS,
                                                       int* __restrict__ bsD,
                                                       int nb, int Etot) {
    __shared__ int s[TPB];
    const int t = threadIdx.x;
    int* hist = blockIdx.x ? histD : histS;
    int* bs   = blockIdx.x ? bsD   : bsS;
    int run = 0;
    for (int blk = 0; blk < nb; ++blk) {
        const int idx = blk * NBUK + t;
        const int v = hist[idx];
        hist[idx] = run;                       // local prefix (per bucket column)
        run += v;
    }
    s[t] = run;
    __syncthreads();
    for (int d = 1; d < TPB; d <<= 1) {
        const int a = (t >= d) ? s[t - d] : 0;
        __syncthreads();
        s[t] += a;
        __syncthreads();
    }
    const int start = s[t] - run;              // exclusive bucket start
    bs[t] = start;
    if (t == TPB - 1) bs[NBUK] = Etot;
    for (int blk = 0; blk < nb; ++blk)
        hist[blk * NBUK + t] += start;
}

// Partition edges into coarse buckets. LDS cursors -> contiguous per-(block,
// bucket) runs -> full-line stores, zero global atomics.
__global__ __launch_bounds__(TPB) void scatter_kernel(const int* __restrict__ src32,
                                                      const int* __restrict__ dst32,
                                                      long long E, int chunk,
                                                      const int* __restrict__ baseS,
                                                      const int* __restrict__ baseD,
                                                      u64* __restrict__ partS,
                                                      int* __restrict__ partD) {
    __shared__ int cs[NBUK], cd[NBUK];
    const int t = threadIdx.x;
    cs[t] = baseS[blockIdx.x * NBUK + t];
    cd[t] = baseD[blockIdx.x * NBUK + t];
    __syncthreads();
    const long long b0 = (long long)blockIdx.x * chunk;
    for (int i = t; i < chunk; i += TPB) {
        const long long e = b0 + i;
        if (e < E) {
            const int sv = src32[e], dv = dst32[e];
            const int ps = atomicAdd(&cs[sv >> 9], 1);   // LDS atomic
            partS[ps] = ((u64)(unsigned)dv << 32) | (unsigned)sv;
            const int pd = atomicAdd(&cd[dv >> 9], 1);
            partD[pd] = dv;
        }
    }
}

// Per-bucket counting sort: offS/cntS + eDst. One block per bucket; bucket
// edge region (~32KB pairs) is L2-hot for the second pass.
__global__ __launch_bounds__(TPB) void csr_kernel(const u64* __restrict__ partS,
                                                  const int* __restrict__ bsS,
                                                  int* __restrict__ offS,
                                                  int* __restrict__ cntS,
                                                  int* __restrict__ eDst, int N) {
    __shared__ int cnt[BWID], off[BWID], s[TPB];
    const int t = threadIdx.x;
    const int B = blockIdx.x;
    const int lo = B * BWID;
    if (lo >= N) return;
    const int eb = bsS[B], ee = bsS[B + 1];
    cnt[t] = 0; cnt[t + TPB] = 0;
    __syncthreads();
    for (int e = eb + t; e < ee; e += TPB)
        atomicAdd(&cnt[(int)(partS[e] & 0xffffffffu) - lo], 1);
    __syncthreads();
    const int c0 = cnt[2 * t], c1 = cnt[2 * t + 1];
    const int loc = c0 + c1;
    s[t] = loc;
    __syncthreads();
    for (int d = 1; d < TPB; d <<= 1) {
        const int a = (t >= d) ? s[t - d] : 0;
        __syncthreads();
        s[t] += a;
        __syncthreads();
    }
    const int ex = s[t] - loc;
    off[2 * t] = ex;
    off[2 * t + 1] = ex + c0;
    __syncthreads();
    for (int i = t; i < BWID; i += TPB) {
        const int node = lo + i;
        if (node < N) { offS[node] = eb + off[i]; cntS[node] = cnt[i]; }
    }
    __syncthreads();
    for (int e = eb + t; e < ee; e += TPB) {
        const u64 p = partS[e];
        const int sv = (int)(p & 0xffffffffu);
        const int dv = (int)(p >> 32);
        const int pos = atomicAdd(&off[sv - lo], 1);     // LDS atomic
        eDst[eb + pos] = dv;
    }
}

// Per-bucket in-degree count -> invd, from the dst partition.
__global__ __launch_bounds__(TPB) void deg_kernel(const int* __restrict__ partD,
                                                  const int* __restrict__ bsD,
                                                  float* __restrict__ invd, int N) {
    __shared__ int cnt[BWID];
    const int t = threadIdx.x;
    const int B = blockIdx.x;
    const int lo = B * BWID;
    if (lo >= N) return;
    const int db = bsD[B], de = bsD[B + 1];
    cnt[t] = 0; cnt[t + TPB] = 0;
    __syncthreads();
    for (int e = db + t; e < de; e += TPB)
        atomicAdd(&cnt[partD[e] - lo], 1);
    __syncthreads();
    for (int i = t; i < BWID; i += TPB) {
        const int node = lo + i;
        if (node < N) invd[node] = 1.0f / (float)(cnt[i] + 1);
    }
}

// W (f32, [128][128]) -> fp16
__global__ void wprep_kernel(const float* __restrict__ W, _Float16* __restrict__ W16) {
    int i = blockIdx.x * TPB + threadIdx.x;   // 16384 total
    W16[i] = (_Float16)W[i];
}

// hn[i][:] = bf16( (x[i] @ W^T) * invd[i] )  via mfma_f32_16x16x32_f16.
__global__ __launch_bounds__(TPB) void gemm_mfma_kernel(const float* __restrict__ x,
                                                        const _Float16* __restrict__ W16,
                                                        const float* __restrict__ invd,
                                                        unsigned short* __restrict__ hn,
                                                        int N) {
    const int t = threadIdx.x;
    const int lane = t & 63;
    const int wid = t >> 6;
    const int lr = lane & 15;      // row (A) / col (B) within fragment
    const int lk = lane >> 4;      // k-block (0..3)
    const int m0 = blockIdx.x * 128 + wid * 32;

    half8 a[2][4];
#pragma unroll
    for (int mb = 0; mb < 2; ++mb) {
        const int row = m0 + mb * 16 + lr;
        const float* xp = x + (size_t)row * C + lk * 8;
#pragma unroll
        for (int ks = 0; ks < 4; ++ks) {
            half8 av;
            if (row < N) {
                const float4 v0 = *(const float4*)(xp + ks * 32);
                const float4 v1 = *(const float4*)(xp + ks * 32 + 4);
                av[0] = (_Float16)v0.x; av[1] = (_Float16)v0.y;
                av[2] = (_Float16)v0.z; av[3] = (_Float16)v0.w;
                av[4] = (_Float16)v1.x; av[5] = (_Float16)v1.y;
                av[6] = (_Float16)v1.z; av[7] = (_Float16)v1.w;
            } else {
                av = (half8)((_Float16)0.f);
            }
            a[mb][ks] = av;
        }
    }

    f32x4 acc[2][8];
#pragma unroll
    for (int mb = 0; mb < 2; ++mb)
#pragma unroll
        for (int nf = 0; nf < 8; ++nf)
            acc[mb][nf] = (f32x4){0.f, 0.f, 0.f, 0.f};

#pragma unroll
    for (int nf = 0; nf < 8; ++nf) {
        half8 b[4];
        const _Float16* wp = W16 + (size_t)(nf * 16 + lr) * C + lk * 8;
#pragma unroll
        for (int ks = 0; ks < 4; ++ks)
            b[ks] = *(const half8*)(wp + ks * 32);
#pragma unroll
        for (int mb = 0; mb < 2; ++mb)
#pragma unroll
            for (int ks = 0; ks < 4; ++ks)
                acc[mb][nf] = __builtin_amdgcn_mfma_f32_16x16x32_f16(
                    a[mb][ks], b[ks], acc[mb][nf], 0, 0, 0);
    }

#pragma unroll
    for (int mb = 0; mb < 2; ++mb) {
#pragma unroll
        for (int r = 0; r < 4; ++r) {
            const int row = m0 + mb * 16 + lk * 4 + r;
            if (row < N) {
                const float idv = invd[row];
                unsigned short* hp = hn + (size_t)row * C + lr;
#pragma unroll
                for (int nf = 0; nf < 8; ++nf)
                    hp[nf * 16] = (unsigned short)f2bf_bits(acc[mb][nf][r] * idv);
            }
        }
    }
}

// One wave per node: out[i] = (sum_{j in adj[i]} hn[j] + hn[i]) * invd[i]
__global__ __launch_bounds__(TPB) void gather_kernel(const int* __restrict__ offS,
                                                     const int* __restrict__ cntS,
                                                     const int* __restrict__ eDst,
                                                     const unsigned* __restrict__ hnb,
                                                     const float* __restrict__ invd,
                                                     float* __restrict__ out, int N) {
    const int lane = threadIdx.x & 63;
    const int w = (blockIdx.x * TPB + threadIdx.x) >> 6;
    if (w >= N) return;
    const int beg = offS[w];
    const int cnt = cntS[w];

    float2 acc = bf2f(hnb[(size_t)w * 64 + lane]);   // self loop

    for (int j0 = 0; j0 < cnt; j0 += 64) {
        const int m = min(64, cnt - j0);
        int dl = 0;
        if (lane < m) dl = eDst[beg + j0 + lane];    // one coalesced load per 64 nbrs
        int q = 0;
#pragma unroll 1
        for (; q + 8 <= m; q += 8) {
            const int d0 = __shfl(dl, q + 0);
            const int d1 = __shfl(dl, q + 1);
            const int d2 = __shfl(dl, q + 2);
            const int d3 = __shfl(dl, q + 3);
            const int d4 = __shfl(dl, q + 4);
            const int d5 = __shfl(dl, q + 5);
            const int d6 = __shfl(dl, q + 6);
            const int d7 = __shfl(dl, q + 7);
            const unsigned v0 = hnb[(size_t)d0 * 64 + lane];
            const unsigned v1 = hnb[(size_t)d1 * 64 + lane];
            const unsigned v2 = hnb[(size_t)d2 * 64 + lane];
            const unsigned v3 = hnb[(size_t)d3 * 64 + lane];
            const unsigned v4 = hnb[(size_t)d4 * 64 + lane];
            const unsigned v5 = hnb[(size_t)d5 * 64 + lane];
            const unsigned v6 = hnb[(size_t)d6 * 64 + lane];
            const unsigned v7 = hnb[(size_t)d7 * 64 + lane];
            float2 a = bf2f(v0), b = bf2f(v1), c = bf2f(v2), d = bf2f(v3);
            float2 e = bf2f(v4), f = bf2f(v5), g = bf2f(v6), h = bf2f(v7);
            acc.x += ((a.x + b.x) + (c.x + d.x)) + ((e.x + f.x) + (g.x + h.x));
            acc.y += ((a.y + b.y) + (c.y + d.y)) + ((e.y + f.y) + (g.y + h.y));
        }
        for (; q < m; ++q) {
            const int d = __shfl(dl, q);
            const float2 v = bf2f(hnb[(size_t)d * 64 + lane]);
            acc.x += v.x; acc.y += v.y;
        }
    }
    const float s = invd[w];
    *(float2*)(out + (size_t)w * C + lane * 2) = make_float2(acc.x * s, acc.y * s);
}

extern "C" void kernel_launch(void* const* d_in, const int* in_sizes, int n_in,
                              void* d_out, int out_size, void* d_ws, size_t ws_size,
                              hipStream_t stream) {
    const float* x = (const float*)d_in[0];
    const void* edges = d_in[1];
    const float* W = (const float*)d_in[2];
    float* out = (float*)d_out;

    const int N = in_sizes[0] / C;
    const long long E = (long long)in_sizes[1] / 2;

    char* ws = (char*)d_ws;
    int*       flagp = (int*)(ws + OFF_FLAG);
    int*       bsS   = (int*)(ws + OFF_BSS);
    int*       bsD   = (int*)(ws + OFF_BSD);
    int*       histS = (int*)(ws + OFF_HISTS);
    int*       histD = (int*)(ws + OFF_HISTD);
    int*       offS  = (int*)(ws + OFF_OFFS);
    int*       cntS  = (int*)(ws + OFF_CNTS);
    float*     invd  = (float*)(ws + OFF_INVD);
    _Float16*  W16   = (_Float16*)(ws + OFF_W16);
    int*       eDst  = (int*)(ws + OFF_EDST);
    unsigned short* hn = (unsigned short*)(ws + OFF_HN);

    // staging in d_out (dead until gather rewrites every element)
    int* o32   = (int*)d_out;
    int* src32 = o32;
    int* dst32 = o32 + E;
    u64* partS = (u64*)(o32 + 2 * E);
    int* partD = o32 + 6 * E;

    const int nBlkE = (int)((E + TPB - 1) / TPB);           // 6250
    const int chunk = (int)((E + NBUK - 1) / NBUK);         // 6250
    const int nbPart = (int)((E + chunk - 1) / chunk);      // 256

    int nCheck = (int)(E < 4096 ? E : 4096);
    detect_kernel<<<1, TPB, 0, stream>>>((const unsigned int*)edges, nCheck, flagp);
    conv_kernel<<<nBlkE, TPB, 0, stream>>>(edges, flagp, E, src32, dst32);
    hist_kernel<<<nbPart, TPB, 0, stream>>>(src32, dst32, E, chunk, histS, histD);
    scanbase_kernel<<<2, TPB, 0, stream>>>(histS, histD, bsS, bsD, nbPart, (int)E);
    scatter_kernel<<<nbPart, TPB, 0, stream>>>(src32, dst32, E, chunk, histS, histD,
                                               partS, partD);
    csr_kernel<<<NBUK, TPB, 0, stream>>>(partS, bsS, offS, cntS, eDst, N);
    deg_kernel<<<NBUK, TPB, 0, stream>>>(partD, bsD, invd, N);

    wprep_kernel<<<(C * C) / TPB, TPB, 0, stream>>>(W, W16);
    const int nBlkG = (N + 127) / 128;                      // 782
    gemm_mfma_kernel<<<nBlkG, TPB, 0, stream>>>(x, W16, invd, hn, N);

    const int nBlkA = (N * 64 + TPB - 1) / TPB;             // 25000 (wave per node)
    gather_kernel<<<nBlkA, TPB, 0, stream>>>(offS, cntS, eDst, (const unsigned*)hn,
                                             invd, out, N);
}

// Round 8
// 178.973 us; speedup vs baseline: 8.5198x; 1.4416x over previous
//
#include <hip/hip_runtime.h>
#include <hip/hip_bf16.h>

#define C 128            // C_IN == C_OUT == 128
#define TPB 256
#define BWID 512         // nodes per coarse bucket (bucket = node >> 9)
#define NBUK 256         // max buckets: supports N <= 131072

typedef __attribute__((ext_vector_type(8))) _Float16 half8;
typedef __attribute__((ext_vector_type(4))) float f32x4;
typedef unsigned long long u64;

// ---------------- workspace layout (bytes) ----------------
#define OFF_FLAG  0x0        // int      edge-dtype flag
#define OFF_BSS   0x400      // int[257] bucket edge-starts (src partition)
#define OFF_BSD   0xC00      // int[257] bucket edge-starts (dst partition)
#define OFF_CSUM  0x1400     // int[512] column totals (S then D)
#define OFF_HISTS 0x10000    // int[256*256] per-(block,bucket) src counts -> local prefix
#define OFF_HISTD 0x50000    // int[256*256] same for dst
#define OFF_OFFS  0xA0000    // int[N]   CSR row offsets
#define OFF_CNTS  0x110000   // int[N]   out-degree
#define OFF_INVD  0x180000   // float[N] 1/(in-degree+1)
#define OFF_W16   0x1F0000   // f16[128*128] W (32 KB)
#define OFF_EDST  0x200000   // int[E]   CSR adjacency
#define OFF_HN    0x900000   // bf16[N*128] hn = (x@W^T) * invd
// d_out staging (dead until gather rewrites out): src32[E], dst32[E],
// partS u64[E], partD int[E]. 7E ints = 44.8 MB <= out 51.2 MB.

__device__ __forceinline__ unsigned f2bf_bits(float f) {
    unsigned u = __float_as_uint(f);
    return (u + 0x7fffu + ((u >> 16) & 1u)) >> 16;   // RNE
}
__device__ __forceinline__ float2 bf2f(unsigned u) {
    return make_float2(__uint_as_float(u << 16), __uint_as_float(u & 0xffff0000u));
}

// Detect whether edge_index is int64 (high 32-bit words all zero) or int32.
__global__ void detect_kernel(const unsigned int* __restrict__ ew, int nCheck,
                              int* __restrict__ flagp) {
    __shared__ int s;
    if (threadIdx.x == 0) s = 0;
    __syncthreads();
    int any = 0;
    for (int i = threadIdx.x; i < nCheck; i += TPB)
        any |= (ew[2 * i + 1] != 0u);
    if (any) s = 1;              // some high word nonzero -> int32 layout
    __syncthreads();
    if (threadIdx.x == 0) *flagp = s;
}

// Decode edges (int64/int32) -> src32/dst32 AND per-block LDS bucket
// histograms (fused; saves one 12.8MB pass).
__global__ __launch_bounds__(TPB) void hist_kernel(const void* __restrict__ edges,
                                                   const int* __restrict__ flagp,
                                                   long long E, int chunk,
                                                   int* __restrict__ src32,
                                                   int* __restrict__ dst32,
                                                   int* __restrict__ histS,
                                                   int* __restrict__ histD) {
    __shared__ int hs[NBUK], hd[NBUK];
    const int t = threadIdx.x;
    hs[t] = 0; hd[t] = 0;                      // TPB == NBUK
    __syncthreads();
    const int is32 = *flagp;
    const long long b0 = (long long)blockIdx.x * chunk;
    for (int i = t; i < chunk; i += TPB) {
        const long long e = b0 + i;
        if (e < E) {
            int s, d;
            if (is32) {
                const int* p = (const int*)edges;
                s = p[e]; d = p[E + e];
            } else {
                const long long* p = (const long long*)edges;
                s = (int)p[e]; d = (int)p[E + e];
            }
            src32[e] = s;
            dst32[e] = d;
            atomicAdd(&hs[s >> 9], 1);         // LDS atomic
            atomicAdd(&hd[d >> 9], 1);
        }
    }
    __syncthreads();
    histS[blockIdx.x * NBUK + t] = hs[t];
    histD[blockIdx.x * NBUK + t] = hd[t];
}

// Parallel per-bucket column scan: block b (of 2*NBUK) scans column b of
// histS (b<NBUK) or histD. hist[blk][b] -> exclusive prefix over blk;
// column total -> csum.
__global__ __launch_bounds__(TPB) void colscan_kernel(int* __restrict__ histS,
                                                      int* __restrict__ histD,
                                                      int* __restrict__ csum, int nb) {
    __shared__ int s[TPB];
    const int t = threadIdx.x;
    const int which = blockIdx.x >> 8;
    const int b = blockIdx.x & (NBUK - 1);
    int* hist = which ? histD : histS;
    const int v = (t < nb) ? hist[t * NBUK + b] : 0;
    s[t] = v;
    __syncthreads();
    for (int d = 1; d < TPB; d <<= 1) {
        const int a = (t >= d) ? s[t - d] : 0;
        __syncthreads();
        s[t] += a;
        __syncthreads();
    }
    if (t < nb) hist[t * NBUK + b] = s[t] - v;         // exclusive within column
    if (t == TPB - 1) csum[which * NBUK + b] = s[t];   // column total
}

// One block: exclusive scan of the 256 column totals -> bucket starts.
__global__ __launch_bounds__(TPB) void bscan_kernel(const int* __restrict__ csum,
                                                    int* __restrict__ bsS,
                                                    int* __restrict__ bsD, int Etot) {
    __shared__ int s[TPB];
    const int t = threadIdx.x;
    int v = csum[t];
    s[t] = v;
    __syncthreads();
    for (int d = 1; d < TPB; d <<= 1) {
        const int a = (t >= d) ? s[t - d] : 0;
        __syncthreads();
        s[t] += a;
        __syncthreads();
    }
    bsS[t] = s[t] - v;
    if (t == TPB - 1) bsS[NBUK] = Etot;
    __syncthreads();
    v = csum[NBUK + t];
    s[t] = v;
    __syncthreads();
    for (int d = 1; d < TPB; d <<= 1) {
        const int a = (t >= d) ? s[t - d] : 0;
        __syncthreads();
        s[t] += a;
        __syncthreads();
    }
    bsD[t] = s[t] - v;
    if (t == TPB - 1) bsD[NBUK] = Etot;
}

// Partition edges into coarse buckets. LDS cursors = local prefix + bucket
// start -> contiguous per-(block,bucket) runs, zero global atomics.
__global__ __launch_bounds__(TPB) void scatter_kernel(const int* __restrict__ src32,
                                                      const int* __restrict__ dst32,
                                                      long long E, int chunk,
                                                      const int* __restrict__ histS,
                                                      const int* __restrict__ histD,
                                                      const int* __restrict__ bsS,
                                                      const int* __restrict__ bsD,
                                                      u64* __restrict__ partS,
                                                      int* __restrict__ partD) {
    __shared__ int cs[NBUK], cd[NBUK];
    const int t = threadIdx.x;
    cs[t] = histS[blockIdx.x * NBUK + t] + bsS[t];
    cd[t] = histD[blockIdx.x * NBUK + t] + bsD[t];
    __syncthreads();
    const long long b0 = (long long)blockIdx.x * chunk;
    for (int i = t; i < chunk; i += TPB) {
        const long long e = b0 + i;
        if (e < E) {
            const int sv = src32[e], dv = dst32[e];
            const int ps = atomicAdd(&cs[sv >> 9], 1);   // LDS atomic
            partS[ps] = ((u64)(unsigned)dv << 32) | (unsigned)sv;
            const int pd = atomicAdd(&cd[dv >> 9], 1);
            partD[pd] = dv;
        }
    }
}

// Per-bucket counting sort: offS/cntS + eDst. One block per bucket.
__global__ __launch_bounds__(TPB) void csr_kernel(const u64* __restrict__ partS,
                                                  const int* __restrict__ bsS,
                                                  int* __restrict__ offS,
                                                  int* __restrict__ cntS,
                                                  int* __restrict__ eDst, int N) {
    __shared__ int cnt[BWID], off[BWID], s[TPB];
    const int t = threadIdx.x;
    const int B = blockIdx.x;
    const int lo = B * BWID;
    if (lo >= N) return;
    const int eb = bsS[B], ee = bsS[B + 1];
    cnt[t] = 0; cnt[t + TPB] = 0;
    __syncthreads();
    for (int e = eb + t; e < ee; e += TPB)
        atomicAdd(&cnt[(int)(partS[e] & 0xffffffffu) - lo], 1);
    __syncthreads();
    const int c0 = cnt[2 * t], c1 = cnt[2 * t + 1];
    const int loc = c0 + c1;
    s[t] = loc;
    __syncthreads();
    for (int d = 1; d < TPB; d <<= 1) {
        const int a = (t >= d) ? s[t - d] : 0;
        __syncthreads();
        s[t] += a;
        __syncthreads();
    }
    const int ex = s[t] - loc;
    off[2 * t] = ex;
    off[2 * t + 1] = ex + c0;
    __syncthreads();
    for (int i = t; i < BWID; i += TPB) {
        const int node = lo + i;
        if (node < N) { offS[node] = eb + off[i]; cntS[node] = cnt[i]; }
    }
    __syncthreads();
    for (int e = eb + t; e < ee; e += TPB) {
        const u64 p = partS[e];
        const int sv = (int)(p & 0xffffffffu);
        const int dv = (int)(p >> 32);
        const int pos = atomicAdd(&off[sv - lo], 1);     // LDS atomic
        eDst[eb + pos] = dv;
    }
}

// Per-bucket in-degree count -> invd, from the dst partition.
__global__ __launch_bounds__(TPB) void deg_kernel(const int* __restrict__ partD,
                                                  const int* __restrict__ bsD,
                                                  float* __restrict__ invd, int N) {
    __shared__ int cnt[BWID];
    const int t = threadIdx.x;
    const int B = blockIdx.x;
    const int lo = B * BWID;
    if (lo >= N) return;
    const int db = bsD[B], de = bsD[B + 1];
    cnt[t] = 0; cnt[t + TPB] = 0;
    __syncthreads();
    for (int e = db + t; e < de; e += TPB)
        atomicAdd(&cnt[partD[e] - lo], 1);
    __syncthreads();
    for (int i = t; i < BWID; i += TPB) {
        const int node = lo + i;
        if (node < N) invd[node] = 1.0f / (float)(cnt[i] + 1);
    }
}

// W (f32, [128][128]) -> fp16
__global__ void wprep_kernel(const float* __restrict__ W, _Float16* __restrict__ W16) {
    int i = blockIdx.x * TPB + threadIdx.x;   // 16384 total
    W16[i] = (_Float16)W[i];
}

// hn[i][:] = bf16( (x[i] @ W^T) * invd[i] )  via mfma_f32_16x16x32_f16.
__global__ __launch_bounds__(TPB) void gemm_mfma_kernel(const float* __restrict__ x,
                                                        const _Float16* __restrict__ W16,
                                                        const float* __restrict__ invd,
                                                        unsigned short* __restrict__ hn,
                                                        int N) {
    const int t = threadIdx.x;
    const int lane = t & 63;
    const int wid = t >> 6;
    const int lr = lane & 15;      // row (A) / col (B) within fragment
    const int lk = lane >> 4;      // k-block (0..3)
    const int m0 = blockIdx.x * 128 + wid * 32;

    half8 a[2][4];
#pragma unroll
    for (int mb = 0; mb < 2; ++mb) {
        const int row = m0 + mb * 16 + lr;
        const float* xp = x + (size_t)row * C + lk * 8;
#pragma unroll
        for (int ks = 0; ks < 4; ++ks) {
            half8 av;
            if (row < N) {
                const float4 v0 = *(const float4*)(xp + ks * 32);
                const float4 v1 = *(const float4*)(xp + ks * 32 + 4);
                av[0] = (_Float16)v0.x; av[1] = (_Float16)v0.y;
                av[2] = (_Float16)v0.z; av[3] = (_Float16)v0.w;
                av[4] = (_Float16)v1.x; av[5] = (_Float16)v1.y;
                av[6] = (_Float16)v1.z; av[7] = (_Float16)v1.w;
            } else {
                av = (half8)((_Float16)0.f);
            }
            a[mb][ks] = av;
        }
    }

    f32x4 acc[2][8];
#pragma unroll
    for (int mb = 0; mb < 2; ++mb)
#pragma unroll
        for (int nf = 0; nf < 8; ++nf)
            acc[mb][nf] = (f32x4){0.f, 0.f, 0.f, 0.f};

#pragma unroll
    for (int nf = 0; nf < 8; ++nf) {
        half8 b[4];
        const _Float16* wp = W16 + (size_t)(nf * 16 + lr) * C + lk * 8;
#pragma unroll
        for (int ks = 0; ks < 4; ++ks)
            b[ks] = *(const half8*)(wp + ks * 32);
#pragma unroll
        for (int mb = 0; mb < 2; ++mb)
#pragma unroll
            for (int ks = 0; ks < 4; ++ks)
                acc[mb][nf] = __builtin_amdgcn_mfma_f32_16x16x32_f16(
                    a[mb][ks], b[ks], acc[mb][nf], 0, 0, 0);
    }

#pragma unroll
    for (int mb = 0; mb < 2; ++mb) {
#pragma unroll
        for (int r = 0; r < 4; ++r) {
            const int row = m0 + mb * 16 + lk * 4 + r;
            if (row < N) {
                const float idv = invd[row];
                unsigned short* hp = hn + (size_t)row * C + lr;
#pragma unroll
                for (int nf = 0; nf < 8; ++nf)
                    hp[nf * 16] = (unsigned short)f2bf_bits(acc[mb][nf][r] * idv);
            }
        }
    }
}

// One wave per node: out[i] = (sum_{j in adj[i]} hn[j] + hn[i]) * invd[i]
__global__ __launch_bounds__(TPB) void gather_kernel(const int* __restrict__ offS,
                                                     const int* __restrict__ cntS,
                                                     const int* __restrict__ eDst,
                                                     const unsigned* __restrict__ hnb,
                                                     const float* __restrict__ invd,
                                                     float* __restrict__ out, int N) {
    const int lane = threadIdx.x & 63;
    const int w = (blockIdx.x * TPB + threadIdx.x) >> 6;
    if (w >= N) return;
    const int beg = offS[w];
    const int cnt = cntS[w];

    float2 acc = bf2f(hnb[(size_t)w * 64 + lane]);   // self loop

    for (int j0 = 0; j0 < cnt; j0 += 64) {
        const int m = min(64, cnt - j0);
        int dl = 0;
        if (lane < m) dl = eDst[beg + j0 + lane];    // one coalesced load per 64 nbrs
        int q = 0;
#pragma unroll 1
        for (; q + 8 <= m; q += 8) {
            const int d0 = __shfl(dl, q + 0);
            const int d1 = __shfl(dl, q + 1);
            const int d2 = __shfl(dl, q + 2);
            const int d3 = __shfl(dl, q + 3);
            const int d4 = __shfl(dl, q + 4);
            const int d5 = __shfl(dl, q + 5);
            const int d6 = __shfl(dl, q + 6);
            const int d7 = __shfl(dl, q + 7);
            const unsigned v0 = hnb[(size_t)d0 * 64 + lane];
            const unsigned v1 = hnb[(size_t)d1 * 64 + lane];
            const unsigned v2 = hnb[(size_t)d2 * 64 + lane];
            const unsigned v3 = hnb[(size_t)d3 * 64 + lane];
            const unsigned v4 = hnb[(size_t)d4 * 64 + lane];
            const unsigned v5 = hnb[(size_t)d5 * 64 + lane];
            const unsigned v6 = hnb[(size_t)d6 * 64 + lane];
            const unsigned v7 = hnb[(size_t)d7 * 64 + lane];
            float2 a = bf2f(v0), b = bf2f(v1), c = bf2f(v2), d = bf2f(v3);
            float2 e = bf2f(v4), f = bf2f(v5), g = bf2f(v6), h = bf2f(v7);
            acc.x += ((a.x + b.x) + (c.x + d.x)) + ((e.x + f.x) + (g.x + h.x));
            acc.y += ((a.y + b.y) + (c.y + d.y)) + ((e.y + f.y) + (g.y + h.y));
        }
        for (; q < m; ++q) {
            const int d = __shfl(dl, q);
            const float2 v = bf2f(hnb[(size_t)d * 64 + lane]);
            acc.x += v.x; acc.y += v.y;
        }
    }
    const float s = invd[w];
    *(float2*)(out + (size_t)w * C + lane * 2) = make_float2(acc.x * s, acc.y * s);
}

extern "C" void kernel_launch(void* const* d_in, const int* in_sizes, int n_in,
                              void* d_out, int out_size, void* d_ws, size_t ws_size,
                              hipStream_t stream) {
    const float* x = (const float*)d_in[0];
    const void* edges = d_in[1];
    const float* W = (const float*)d_in[2];
    float* out = (float*)d_out;

    const int N = in_sizes[0] / C;
    const long long E = (long long)in_sizes[1] / 2;

    char* ws = (char*)d_ws;
    int*       flagp = (int*)(ws + OFF_FLAG);
    int*       bsS   = (int*)(ws + OFF_BSS);
    int*       bsD   = (int*)(ws + OFF_BSD);
    int*       csum  = (int*)(ws + OFF_CSUM);
    int*       histS = (int*)(ws + OFF_HISTS);
    int*       histD = (int*)(ws + OFF_HISTD);
    int*       offS  = (int*)(ws + OFF_OFFS);
    int*       cntS  = (int*)(ws + OFF_CNTS);
    float*     invd  = (float*)(ws + OFF_INVD);
    _Float16*  W16   = (_Float16*)(ws + OFF_W16);
    int*       eDst  = (int*)(ws + OFF_EDST);
    unsigned short* hn = (unsigned short*)(ws + OFF_HN);

    // staging in d_out (dead until gather rewrites every element)
    int* o32   = (int*)d_out;
    int* src32 = o32;
    int* dst32 = o32 + E;
    u64* partS = (u64*)(o32 + 2 * E);
    int* partD = o32 + 6 * E;

    const int chunk = (int)((E + NBUK - 1) / NBUK);         // 6250
    const int nbPart = (int)((E + chunk - 1) / chunk);      // 256

    int nCheck = (int)(E < 4096 ? E : 4096);
    detect_kernel<<<1, TPB, 0, stream>>>((const unsigned int*)edges, nCheck, flagp);
    hist_kernel<<<nbPart, TPB, 0, stream>>>(edges, flagp, E, chunk, src32, dst32,
                                            histS, histD);
    colscan_kernel<<<2 * NBUK, TPB, 0, stream>>>(histS, histD, csum, nbPart);
    bscan_kernel<<<1, TPB, 0, stream>>>(csum, bsS, bsD, (int)E);
    scatter_kernel<<<nbPart, TPB, 0, stream>>>(src32, dst32, E, chunk, histS, histD,
                                               bsS, bsD, partS, partD);
    csr_kernel<<<NBUK, TPB, 0, stream>>>(partS, bsS, offS, cntS, eDst, N);
    deg_kernel<<<NBUK, TPB, 0, stream>>>(partD, bsD, invd, N);

    wprep_kernel<<<(C * C) / TPB, TPB, 0, stream>>>(W, W16);
    const int nBlkG = (N + 127) / 128;                      // 782
    gemm_mfma_kernel<<<nBlkG, TPB, 0, stream>>>(x, W16, invd, hn, N);

    const int nBlkA = (N * 64 + TPB - 1) / TPB;             // 25000 (wave per node)
    gather_kernel<<<nBlkA, TPB, 0, stream>>>(offS, cntS, eDst, (const unsigned*)hn,
                                             invd, out, N);
}

// Round 10
// 178.634 us; speedup vs baseline: 8.5359x; 1.0019x over previous
//
#include <hip/hip_runtime.h>
#include <hip/hip_bf16.h>

#define C 128            // C_IN == C_OUT == 128
#define TPB 256
#define BWID 512         // nodes per coarse bucket (bucket = node >> 9)
#define NBUK 256         // max buckets: supports N <= 131072

typedef __attribute__((ext_vector_type(8))) _Float16 half8;
typedef __attribute__((ext_vector_type(4))) float f32x4;
typedef __attribute__((ext_vector_type(2))) float fv2;
typedef unsigned long long u64;

// ---------------- workspace layout (bytes) ----------------
#define OFF_FLAG  0x0        // int      edge-dtype flag
#define OFF_BSS   0x400      // int[257] bucket edge-starts (src partition)
#define OFF_BSD   0xC00      // int[257] bucket edge-starts (dst partition)
#define OFF_CSUM  0x1400     // int[512] column totals (S then D)
#define OFF_HISTS 0x10000    // int[256*256] per-(block,bucket) src counts -> local prefix
#define OFF_HISTD 0x50000    // int[256*256] same for dst
#define OFF_OFFS  0xA0000    // int[N]   CSR row offsets
#define OFF_CNTS  0x110000   // int[N]   out-degree
#define OFF_INVD  0x180000   // float[N] 1/(in-degree+1)
#define OFF_W16   0x1F0000   // f16[128*128] W (32 KB)
#define OFF_EDST  0x200000   // int[E]   CSR adjacency
#define OFF_HN    0x900000   // bf16[N*128] hn = (x@W^T) * invd
// d_out staging (dead until gather rewrites out): src32[E], dst32[E],
// partS u64[E], partD int[E]. 7E ints = 44.8 MB <= out 51.2 MB.

__device__ __forceinline__ unsigned f2bf_bits(float f) {
    unsigned u = __float_as_uint(f);
    return (u + 0x7fffu + ((u >> 16) & 1u)) >> 16;   // RNE
}

// Detect whether edge_index is int64 (high 32-bit words all zero) or int32.
__global__ void detect_kernel(const unsigned int* __restrict__ ew, int nCheck,
                              int* __restrict__ flagp) {
    __shared__ int s;
    if (threadIdx.x == 0) s = 0;
    __syncthreads();
    int any = 0;
    for (int i = threadIdx.x; i < nCheck; i += TPB)
        any |= (ew[2 * i + 1] != 0u);
    if (any) s = 1;              // some high word nonzero -> int32 layout
    __syncthreads();
    if (threadIdx.x == 0) *flagp = s;
}

// Decode edges (int64/int32) -> src32/dst32 AND per-block LDS bucket
// histograms (fused; saves one 12.8MB pass).
__global__ __launch_bounds__(TPB) void hist_kernel(const void* __restrict__ edges,
                                                   const int* __restrict__ flagp,
                                                   long long E, int chunk,
                                                   int* __restrict__ src32,
                                                   int* __restrict__ dst32,
                                                   int* __restrict__ histS,
                                                   int* __restrict__ histD) {
    __shared__ int hs[NBUK], hd[NBUK];
    const int t = threadIdx.x;
    hs[t] = 0; hd[t] = 0;                      // TPB == NBUK
    __syncthreads();
    const int is32 = *flagp;
    const long long b0 = (long long)blockIdx.x * chunk;
    for (int i = t; i < chunk; i += TPB) {
        const long long e = b0 + i;
        if (e < E) {
            int s, d;
            if (is32) {
                const int* p = (const int*)edges;
                s = p[e]; d = p[E + e];
            } else {
                const long long* p = (const long long*)edges;
                s = (int)p[e]; d = (int)p[E + e];
            }
            src32[e] = s;
            dst32[e] = d;
            atomicAdd(&hs[s >> 9], 1);         // LDS atomic
            atomicAdd(&hd[d >> 9], 1);
        }
    }
    __syncthreads();
    histS[blockIdx.x * NBUK + t] = hs[t];
    histD[blockIdx.x * NBUK + t] = hd[t];
}

// Parallel per-bucket column scan: block b (of 2*NBUK) scans column b of
// histS (b<NBUK) or histD. hist[blk][b] -> exclusive prefix over blk;
// column total -> csum.
__global__ __launch_bounds__(TPB) void colscan_kernel(int* __restrict__ histS,
                                                      int* __restrict__ histD,
                                                      int* __restrict__ csum, int nb) {
    __shared__ int s[TPB];
    const int t = threadIdx.x;
    const int which = blockIdx.x >> 8;
    const int b = blockIdx.x & (NBUK - 1);
    int* hist = which ? histD : histS;
    const int v = (t < nb) ? hist[t * NBUK + b] : 0;
    s[t] = v;
    __syncthreads();
    for (int d = 1; d < TPB; d <<= 1) {
        const int a = (t >= d) ? s[t - d] : 0;
        __syncthreads();
        s[t] += a;
        __syncthreads();
    }
    if (t < nb) hist[t * NBUK + b] = s[t] - v;         // exclusive within column
    if (t == TPB - 1) csum[which * NBUK + b] = s[t];   // column total
}

// One block: exclusive scan of the 256 column totals -> bucket starts.
__global__ __launch_bounds__(TPB) void bscan_kernel(const int* __restrict__ csum,
                                                    int* __restrict__ bsS,
                                                    int* __restrict__ bsD, int Etot) {
    __shared__ int s[TPB];
    const int t = threadIdx.x;
    int v = csum[t];
    s[t] = v;
    __syncthreads();
    for (int d = 1; d < TPB; d <<= 1) {
        const int a = (t >= d) ? s[t - d] : 0;
        __syncthreads();
        s[t] += a;
        __syncthreads();
    }
    bsS[t] = s[t] - v;
    if (t == TPB - 1) bsS[NBUK] = Etot;
    __syncthreads();
    v = csum[NBUK + t];
    s[t] = v;
    __syncthreads();
    for (int d = 1; d < TPB; d <<= 1) {
        const int a = (t >= d) ? s[t - d] : 0;
        __syncthreads();
        s[t] += a;
        __syncthreads();
    }
    bsD[t] = s[t] - v;
    if (t == TPB - 1) bsD[NBUK] = Etot;
}

// Partition edges into coarse buckets. LDS cursors = local prefix + bucket
// start -> contiguous per-(block,bucket) runs, zero global atomics.
__global__ __launch_bounds__(TPB) void scatter_kernel(const int* __restrict__ src32,
                                                      const int* __restrict__ dst32,
                                                      long long E, int chunk,
                                                      const int* __restrict__ histS,
                                                      const int* __restrict__ histD,
                                                      const int* __restrict__ bsS,
                                                      const int* __restrict__ bsD,
                                                      u64* __restrict__ partS,
                                                      int* __restrict__ partD) {
    __shared__ int cs[NBUK], cd[NBUK];
    const int t = threadIdx.x;
    cs[t] = histS[blockIdx.x * NBUK + t] + bsS[t];
    cd[t] = histD[blockIdx.x * NBUK + t] + bsD[t];
    __syncthreads();
    const long long b0 = (long long)blockIdx.x * chunk;
    for (int i = t; i < chunk; i += TPB) {
        const long long e = b0 + i;
        if (e < E) {
            const int sv = src32[e], dv = dst32[e];
            const int ps = atomicAdd(&cs[sv >> 9], 1);   // LDS atomic
            partS[ps] = ((u64)(unsigned)dv << 32) | (unsigned)sv;
            const int pd = atomicAdd(&cd[dv >> 9], 1);
            partD[pd] = dv;
        }
    }
}

// Per-bucket counting sort: offS/cntS + eDst. One block per bucket.
__global__ __launch_bounds__(TPB) void csr_kernel(const u64* __restrict__ partS,
                                                  const int* __restrict__ bsS,
                                                  int* __restrict__ offS,
                                                  int* __restrict__ cntS,
                                                  int* __restrict__ eDst, int N) {
    __shared__ int cnt[BWID], off[BWID], s[TPB];
    const int t = threadIdx.x;
    const int B = blockIdx.x;
    const int lo = B * BWID;
    if (lo >= N) return;
    const int eb = bsS[B], ee = bsS[B + 1];
    cnt[t] = 0; cnt[t + TPB] = 0;
    __syncthreads();
    for (int e = eb + t; e < ee; e += TPB)
        atomicAdd(&cnt[(int)(partS[e] & 0xffffffffu) - lo], 1);
    __syncthreads();
    const int c0 = cnt[2 * t], c1 = cnt[2 * t + 1];
    const int loc = c0 + c1;
    s[t] = loc;
    __syncthreads();
    for (int d = 1; d < TPB; d <<= 1) {
        const int a = (t >= d) ? s[t - d] : 0;
        __syncthreads();
        s[t] += a;
        __syncthreads();
    }
    const int ex = s[t] - loc;
    off[2 * t] = ex;
    off[2 * t + 1] = ex + c0;
    __syncthreads();
    for (int i = t; i < BWID; i += TPB) {
        const int node = lo + i;
        if (node < N) { offS[node] = eb + off[i]; cntS[node] = cnt[i]; }
    }
    __syncthreads();
    for (int e = eb + t; e < ee; e += TPB) {
        const u64 p = partS[e];
        const int sv = (int)(p & 0xffffffffu);
        const int dv = (int)(p >> 32);
        const int pos = atomicAdd(&off[sv - lo], 1);     // LDS atomic
        eDst[eb + pos] = dv;
    }
}

// Per-bucket in-degree count -> invd, from the dst partition.
__global__ __launch_bounds__(TPB) void deg_kernel(const int* __restrict__ partD,
                                                  const int* __restrict__ bsD,
                                                  float* __restrict__ invd, int N) {
    __shared__ int cnt[BWID];
    const int t = threadIdx.x;
    const int B = blockIdx.x;
    const int lo = B * BWID;
    if (lo >= N) return;
    const int db = bsD[B], de = bsD[B + 1];
    cnt[t] = 0; cnt[t + TPB] = 0;
    __syncthreads();
    for (int e = db + t; e < de; e += TPB)
        atomicAdd(&cnt[partD[e] - lo], 1);
    __syncthreads();
    for (int i = t; i < BWID; i += TPB) {
        const int node = lo + i;
        if (node < N) invd[node] = 1.0f / (float)(cnt[i] + 1);
    }
}

// W (f32, [128][128]) -> fp16
__global__ void wprep_kernel(const float* __restrict__ W, _Float16* __restrict__ W16) {
    int i = blockIdx.x * TPB + threadIdx.x;   // 16384 total
    W16[i] = (_Float16)W[i];
}

// hn[i][:] = bf16( (x[i] @ W^T) * invd[i] )  via mfma_f32_16x16x32_f16.
__global__ __launch_bounds__(TPB) void gemm_mfma_kernel(const float* __restrict__ x,
                                                        const _Float16* __restrict__ W16,
                                                        const float* __restrict__ invd,
                                                        unsigned short* __restrict__ hn,
                                                        int N) {
    const int t = threadIdx.x;
    const int lane = t & 63;
    const int wid = t >> 6;
    const int lr = lane & 15;      // row (A) / col (B) within fragment
    const int lk = lane >> 4;      // k-block (0..3)
    const int m0 = blockIdx.x * 128 + wid * 32;

    half8 a[2][4];
#pragma unroll
    for (int mb = 0; mb < 2; ++mb) {
        const int row = m0 + mb * 16 + lr;
        const float* xp = x + (size_t)row * C + lk * 8;
#pragma unroll
        for (int ks = 0; ks < 4; ++ks) {
            half8 av;
            if (row < N) {
                const float4 v0 = *(const float4*)(xp + ks * 32);
                const float4 v1 = *(const float4*)(xp + ks * 32 + 4);
                av[0] = (_Float16)v0.x; av[1] = (_Float16)v0.y;
                av[2] = (_Float16)v0.z; av[3] = (_Float16)v0.w;
                av[4] = (_Float16)v1.x; av[5] = (_Float16)v1.y;
                av[6] = (_Float16)v1.z; av[7] = (_Float16)v1.w;
            } else {
                av = (half8)((_Float16)0.f);
            }
            a[mb][ks] = av;
        }
    }

    f32x4 acc[2][8];
#pragma unroll
    for (int mb = 0; mb < 2; ++mb)
#pragma unroll
        for (int nf = 0; nf < 8; ++nf)
            acc[mb][nf] = (f32x4){0.f, 0.f, 0.f, 0.f};

#pragma unroll
    for (int nf = 0; nf < 8; ++nf) {
        half8 b[4];
        const _Float16* wp = W16 + (size_t)(nf * 16 + lr) * C + lk * 8;
#pragma unroll
        for (int ks = 0; ks < 4; ++ks)
            b[ks] = *(const half8*)(wp + ks * 32);
#pragma unroll
        for (int mb = 0; mb < 2; ++mb)
#pragma unroll
            for (int ks = 0; ks < 4; ++ks)
                acc[mb][nf] = __builtin_amdgcn_mfma_f32_16x16x32_f16(
                    a[mb][ks], b[ks], acc[mb][nf], 0, 0, 0);
    }

#pragma unroll
    for (int mb = 0; mb < 2; ++mb) {
#pragma unroll
        for (int r = 0; r < 4; ++r) {
            const int row = m0 + mb * 16 + lk * 4 + r;
            if (row < N) {
                const float idv = invd[row];
                unsigned short* hp = hn + (size_t)row * C + lr;
#pragma unroll
                for (int nf = 0; nf < 8; ++nf)
                    hp[nf * 16] = (unsigned short)f2bf_bits(acc[mb][nf][r] * idv);
            }
        }
    }
}

// One wave per node. Lane = (sub, ll): 16 lanes x uint4 = one 256B hn row,
// 4 sub-groups process 4 neighbors per memory instruction. Self-loop is a
// virtual (cnt+1)-th item. Cross-sub reduce via shfl_xor(16/32).
// out stores & eDst loads are non-temporal (write/read-once) to keep L2
// capacity for the 25.6MB hn table.
__global__ __launch_bounds__(TPB) void gather_kernel(const int* __restrict__ offS,
                                                     const int* __restrict__ cntS,
                                                     const int* __restrict__ eDst,
                                                     const uint4* __restrict__ hnb4,
                                                     const float* __restrict__ invd,
                                                     float* __restrict__ out, int N) {
    const int lane = threadIdx.x & 63;
    const int w = (blockIdx.x * TPB + threadIdx.x) >> 6;
    if (w >= N) return;
    const int sub = lane >> 4;     // 0..3: neighbor within group of 4
    const int ll  = lane & 15;     // 16B chunk within row
    const int beg = offS[w];
    const int cnt = cntS[w];
    const int total = cnt + 1;     // + self loop

    float acc[8];
#pragma unroll
    for (int i = 0; i < 8; ++i) acc[i] = 0.f;

    for (int j0 = 0; j0 < total; j0 += 64) {
        const int m = min(64, total - j0);
        int dl = w;                                      // virtual self item
        if (lane < m && j0 + lane < cnt)
            dl = __builtin_nontemporal_load(&eDst[beg + j0 + lane]);
#pragma unroll 1
        for (int q = 0; q < m; q += 4) {
            const int d = __shfl(dl, q + sub);
            if (q + sub < m) {
                const uint4 v = hnb4[(size_t)d * 16 + ll];
                acc[0] += __uint_as_float(v.x << 16);
                acc[1] += __uint_as_float(v.x & 0xffff0000u);
                acc[2] += __uint_as_float(v.y << 16);
                acc[3] += __uint_as_float(v.y & 0xffff0000u);
                acc[4] += __uint_as_float(v.z << 16);
                acc[5] += __uint_as_float(v.z & 0xffff0000u);
                acc[6] += __uint_as_float(v.w << 16);
                acc[7] += __uint_as_float(v.w & 0xffff0000u);
            }
        }
    }

#pragma unroll
    for (int i = 0; i < 8; ++i) {
        acc[i] += __shfl_xor(acc[i], 16);
        acc[i] += __shfl_xor(acc[i], 32);
    }

    const float s = invd[w];
    fv2 o;
    o.x = acc[sub * 2] * s;
    o.y = acc[sub * 2 + 1] * s;
    fv2* op = (fv2*)(out + (size_t)w * C + ll * 8 + sub * 2);
    __builtin_nontemporal_store(o, op);
}

extern "C" void kernel_launch(void* const* d_in, const int* in_sizes, int n_in,
                              void* d_out, int out_size, void* d_ws, size_t ws_size,
                              hipStream_t stream) {
    const float* x = (const float*)d_in[0];
    const void* edges = d_in[1];
    const float* W = (const float*)d_in[2];
    float* out = (float*)d_out;

    const int N = in_sizes[0] / C;
    const long long E = (long long)in_sizes[1] / 2;

    char* ws = (char*)d_ws;
    int*       flagp = (int*)(ws + OFF_FLAG);
    int*       bsS   = (int*)(ws + OFF_BSS);
    int*       bsD   = (int*)(ws + OFF_BSD);
    int*       csum  = (int*)(ws + OFF_CSUM);
    int*       histS = (int*)(ws + OFF_HISTS);
    int*       histD = (int*)(ws + OFF_HISTD);
    int*       offS  = (int*)(ws + OFF_OFFS);
    int*       cntS  = (int*)(ws + OFF_CNTS);
    float*     invd  = (float*)(ws + OFF_INVD);
    _Float16*  W16   = (_Float16*)(ws + OFF_W16);
    int*       eDst  = (int*)(ws + OFF_EDST);
    unsigned short* hn = (unsigned short*)(ws + OFF_HN);

    // staging in d_out (dead until gather rewrites every element)
    int* o32   = (int*)d_out;
    int* src32 = o32;
    int* dst32 = o32 + E;
    u64* partS = (u64*)(o32 + 2 * E);
    int* partD = o32 + 6 * E;

    const int chunk = (int)((E + NBUK - 1) / NBUK);         // 6250
    const int nbPart = (int)((E + chunk - 1) / chunk);      // 256

    int nCheck = (int)(E < 4096 ? E : 4096);
    detect_kernel<<<1, TPB, 0, stream>>>((const unsigned int*)edges, nCheck, flagp);
    hist_kernel<<<nbPart, TPB, 0, stream>>>(edges, flagp, E, chunk, src32, dst32,
                                            histS, histD);
    colscan_kernel<<<2 * NBUK, TPB, 0, stream>>>(histS, histD, csum, nbPart);
    bscan_kernel<<<1, TPB, 0, stream>>>(csum, bsS, bsD, (int)E);
    scatter_kernel<<<nbPart, TPB, 0, stream>>>(src32, dst32, E, chunk, histS, histD,
                                               bsS, bsD, partS, partD);
    csr_kernel<<<NBUK, TPB, 0, stream>>>(partS, bsS, offS, cntS, eDst, N);
    deg_kernel<<<NBUK, TPB, 0, stream>>>(partD, bsD, invd, N);

    wprep_kernel<<<(C * C) / TPB, TPB, 0, stream>>>(W, W16);
    const int nBlkG = (N + 127) / 128;                      // 782
    gemm_mfma_kernel<<<nBlkG, TPB, 0, stream>>>(x, W16, invd, hn, N);

    const int nBlkA = (N * 64 + TPB - 1) / TPB;             // 25000 (wave per node)
    gather_kernel<<<nBlkA, TPB, 0, stream>>>(offS, cntS, eDst, (const uint4*)hn,
                                             invd, out, N);
}